// Round 12
// baseline (7346.064 us; speedup 1.0000x reference)
//
#include <hip/hip_runtime.h>

#define DEVI __device__ __forceinline__

typedef __attribute__((ext_vector_type(8))) __bf16 bf16x8;
typedef __attribute__((ext_vector_type(4))) float f32x4;

// ---------- scalar helpers ----------
DEVI unsigned short f2b(float f) {           // f32 -> bf16 (RNE)
  unsigned u = __float_as_uint(f);
  u = u + 0x7fffu + ((u >> 16) & 1u);
  return (unsigned short)(u >> 16);
}
DEVI float lo16(unsigned u) { return __uint_as_float(u << 16); }
DEVI float hi16(unsigned u) { return __uint_as_float(u & 0xffff0000u); }
#if __has_builtin(__builtin_amdgcn_rcpf)
DEVI float rcpf(float x) { return __builtin_amdgcn_rcpf(x); }
#else
DEVI float rcpf(float x) { return 1.f / x; }
#endif
DEVI float sigm(float x) { return rcpf(1.f + __expf(-x)); }
DEVI float tanh_f(float x) { return fmaf(2.f, rcpf(1.f + __expf(-2.f * x)), -1.f); }

// ---------- fp8 e4m3fn encode ----------
#if __has_builtin(__builtin_amdgcn_cvt_pk_fp8_f32)
DEVI unsigned char f2e4m3(float f) {
  return (unsigned char)(__builtin_amdgcn_cvt_pk_fp8_f32(f, f, 0, false) & 0xff);
}
#else
DEVI unsigned char f2e4m3(float f) {   // software RNE e4m3fn
  unsigned u = __float_as_uint(f);
  unsigned s = (u >> 31) << 7;
  float a = fabsf(f);
  if (a >= 448.f) return (unsigned char)(s | 0x7e);
  if (a < 0.015625f) {                 // denorm, unit 2^-9
    int m = (int)rintf(a * 512.f);
    if (m >= 8) return (unsigned char)(s | 0x08);
    return (unsigned char)(s | m);
  }
  unsigned ur = u + 0x7FFFF + ((u >> 20) & 1);   // RNE at mantissa bit 20
  int e8 = (int)((ur >> 23) & 255) - 127 + 7;
  unsigned m3 = (ur >> 20) & 7;
  if (e8 > 15 || (e8 == 15 && m3 > 6)) return (unsigned char)(s | 0x7e);
  if (e8 <= 0) return (unsigned char)s;
  return (unsigned char)(s | (e8 << 3) | m3);
}
#endif

// ---------- prep kernels ----------
__global__ void cvt_bf16(const float* __restrict__ in, unsigned short* __restrict__ out, int n) {
  for (int i = blockIdx.x * blockDim.x + threadIdx.x; i < n; i += gridDim.x * blockDim.x)
    out[i] = f2b(in[i]);
}

// Whh (2,1024,256) f32 -> fp8 MFMA-A-fragment order:
// uint2 index = ((d*64 + mt)*8 + kf)*64 + lane; bytes j=0..7:
//   row = mt*16 + (lane&15); unit = row>>2; gate = row&3;
//   k = kf*32 + (lane>>4)*8 + j;  src = W[d][gate*256 + unit][k]
__global__ void whh_pack(const float* __restrict__ W, uint2* __restrict__ out) {
  int idx = blockIdx.x * blockDim.x + threadIdx.x;   // 65536 total
  if (idx >= 65536) return;
  int d = idx >> 15, rem = idx & 32767;
  int mt = rem >> 9, kf = (rem >> 6) & 7, lane = rem & 63;
  int row = mt * 16 + (lane & 15);
  int unit = row >> 2, gate = row & 3;
  int kb = kf * 32 + (lane >> 4) * 8;
  const float* w = W + (((size_t)d * 1024 + gate * 256 + unit) * 256 + kb);
  unsigned lo = 0, hi = 0;
  #pragma unroll
  for (int j = 0; j < 4; ++j) lo |= (unsigned)f2e4m3(w[j]) << (8 * j);
  #pragma unroll
  for (int j = 0; j < 4; ++j) hi |= (unsigned)f2e4m3(w[4 + j]) << (8 * j);
  out[idx] = make_uint2(lo, hi);
}

__global__ void bias_sum(const float* __restrict__ a, const float* __restrict__ b,
                         float* __restrict__ o, int n) {
  int i = blockIdx.x * blockDim.x + threadIdx.x;
  if (i < n) o[i] = a[i] + b[i];
}

__global__ void embed_gather(const int* __restrict__ ids, const float* __restrict__ tab,
                             unsigned short* __restrict__ out, int total) {
  for (int i = blockIdx.x * blockDim.x + threadIdx.x; i < total; i += gridDim.x * blockDim.x) {
    int bt = i >> 7, c = i & 127;
    out[i] = f2b(tab[(size_t)ids[bt] * 128 + c]);
  }
}

// ---------- GEMM (LDS-staged): C[M,N] = act(A[M,K](lda,bf16) @ W[N,K]^T + bias) -> bf16
// 128x128 tile, 256 thr (4 waves), K-step 32. A,B staged via reg->LDS with XOR chunk
// swizzle (2-way bank aliasing on frag reads = free, m136). Wave w: rows w*32..+31,
// all 128 cols: 2 A-frags x 8 B-frags, 16 MFMA/K-step, 64 AGPR acc.
template <int ACT, int PERM>
__global__ __launch_bounds__(256) void gemm_lds(const unsigned short* __restrict__ A, int lda,
                                                const unsigned short* __restrict__ W,
                                                const float* __restrict__ bias,
                                                unsigned short* __restrict__ C,
                                                int M, int N, int K) {
  const int ntiles = N >> 7;
  const int mt = blockIdx.x / ntiles;
  const int nt = blockIdx.x - mt * ntiles;
  const int m0 = mt << 7, n0 = nt << 7;
  const int tid = threadIdx.x;
  const int w = tid >> 6, lane = tid & 63, r = lane & 15, q = lane >> 4;
  __shared__ unsigned short lsA[4096], lsB[4096];   // 128 rows x 32 (16B chunks swizzled)
  f32x4 acc[16];
  #pragma unroll
  for (int i = 0; i < 16; ++i) acc[i] = f32x4{0.f, 0.f, 0.f, 0.f};

  // staging: thread handles rows (tid>>2) and 64+(tid>>2), k-chunk (tid&3)
  const int srow = tid >> 2, sq = tid & 3;
  const int s0 = (srow << 2) | (sq ^ (srow & 3) ^ ((srow >> 2) & 3));   // swizzled slot
  const unsigned short* gA = A + (size_t)(m0 + srow) * lda + sq * 8;
  const unsigned short* gB = W + (size_t)(n0 + srow) * K + sq * 8;
  const size_t gAs = (size_t)64 * lda, gBs = (size_t)64 * K;
  // frag-read swizzle bits (same for all frags: row offsets are multiples of 16)
  const int sw = q ^ (r & 3) ^ ((r >> 2) & 3);

  for (int k0 = 0; k0 < K; k0 += 32) {
    uint4 va0 = *(const uint4*)(gA + k0);
    uint4 va1 = *(const uint4*)(gA + gAs + k0);
    uint4 vb0 = *(const uint4*)(gB + k0);
    uint4 vb1 = *(const uint4*)(gB + gBs + k0);
    *(uint4*)(lsA + s0 * 8) = va0;
    *(uint4*)(lsA + s0 * 8 + 2048) = va1;
    *(uint4*)(lsB + s0 * 8) = vb0;
    *(uint4*)(lsB + s0 * 8 + 2048) = vb1;
    __syncthreads();
    const bf16x8 a0 = *(const bf16x8*)(const void*)(lsA + ((w * 32 + r) * 4 + sw) * 8);
    const bf16x8 a1 = *(const bf16x8*)(const void*)(lsA + ((w * 32 + 16 + r) * 4 + sw) * 8);
    #pragma unroll
    for (int nf = 0; nf < 8; ++nf) {
      const bf16x8 b = *(const bf16x8*)(const void*)(lsB + ((nf * 16 + r) * 4 + sw) * 8);
      acc[nf]     = __builtin_amdgcn_mfma_f32_16x16x32_bf16(a0, b, acc[nf], 0, 0, 0);
      acc[8 + nf] = __builtin_amdgcn_mfma_f32_16x16x32_bf16(a1, b, acc[8 + nf], 0, 0, 0);
    }
    __syncthreads();
  }
  // D layout (m89-verified): col = lane&15, row = (lane>>4)*4 + reg
  #pragma unroll
  for (int mf = 0; mf < 2; ++mf) {
    const int rbase = m0 + w * 32 + mf * 16 + q * 4;
    #pragma unroll
    for (int nf = 0; nf < 8; ++nf) {
      const f32x4 a = acc[mf * 8 + nf];
      const int col = n0 + nf * 16 + r;
      const float bv = bias[col];
      int oc = col;
      if constexpr (PERM) oc = (col & 1024) | ((col & 255) << 2) | ((col >> 8) & 3);
      #pragma unroll
      for (int i = 0; i < 4; ++i) {
        float v = a[i] + bv;
        if constexpr (ACT) v = fmaxf(v, 0.f);
        C[(size_t)(rbase + i) * N + oc] = f2b(v);
      }
    }
  }
}

// ---------- LSTM recurrence via MFMA fp8, 16 samples per block ----------
// Block = (pathway, dir, sample-group of 16). 1024 threads = 16 waves, 1 block/CU.
// Wave w owns M-tiles w*4+j => units w*16+j*4+q; lane (q,n) holds all 4 gates of
// unit, sample n (C/D: col=lane&15, row=(lane>>4)*4+reg). c-state in registers.
// WEIGHTS: waves 0..7 read their 16KB slice from LDS (loaded once, 128 KB);
// waves 8..15 stream from L2 -> per-step L2 traffic halved (256->128 KB).
// h: fp8 B-frags in LDS ping-pong (MFMA input) + bf16 rows in hout (coalesced store).
// xg prefetched one step ahead. One barrier per step. R9-form cell update.
__global__ __launch_bounds__(1024, 4) void lstm_mfma(
    const uint2* __restrict__ W0, const unsigned short* __restrict__ x0,
    unsigned short* __restrict__ o0, int oo0,
    const uint2* __restrict__ W1, const unsigned short* __restrict__ x1,
    unsigned short* __restrict__ o1, int oo1, int T) {
  const int bid = blockIdx.x;
  const int sg = bid & 3, dir = (bid >> 2) & 1, grp = bid >> 3;
  const uint2* __restrict__ Wp = (grp ? W1 : W0) + (size_t)dir * 32768;
  const unsigned short* __restrict__ xg = grp ? x1 : x0;
  unsigned short* __restrict__ out = grp ? o1 : o0;
  const int outOff = grp ? oo1 : oo0;

  const int tid = threadIdx.x;
  const int w = tid >> 6, lane = tid & 63, q = lane >> 4, n = lane & 15;
  const int b = sg * 16 + n;

  __shared__ long hb[2][512];                 // fp8 h B-fragments (MFMA input)
  __shared__ unsigned short hout[2][16][264]; // bf16 h rows, padded (store staging)
  __shared__ long wlds[16384];                // waves 0..7 weight slices (128 KB)
  hb[0][tid & 511] = 0;
  hb[1][tid & 511] = 0;
  if (w < 8) {
    const uint2* ap = Wp + (size_t)(w * 32) * 64 + lane;
    #pragma unroll
    for (int i = 0; i < 32; ++i)
      wlds[w * 2048 + i * 64 + lane] = __builtin_bit_cast(long, ap[(size_t)i * 64]);
  }

  float c[4] = {0.f, 0.f, 0.f, 0.f};
  const unsigned short* xb = xg + ((size_t)b * T) * 2048 + dir * 1024 + (w * 16 + q) * 4;
  // wave w cooperatively stores sample (sg*16+w)'s output row
  unsigned short* orow = out + ((size_t)(sg * 16 + w) * T) * 1024 + outOff + dir * 256 + lane * 4;

  const int tstep = dir ? -1 : 1;
  int t = dir ? T - 1 : 0;
  // prefetch first step's xg
  uint2 xv[4];
  #pragma unroll
  for (int j = 0; j < 4; ++j)
    xv[j] = *(const uint2*)(xb + (size_t)t * 2048 + j * 16);
  __syncthreads();

  int cur = 0;
  for (int ti = 0; ti < T; ++ti) {
    // coalesced store of previous step's h (written into hout[cur] last iter)
    if (ti) {
      const uint2 hv = *(const uint2*)&hout[cur][w][lane * 4];
      *(uint2*)(orow + (size_t)(t - tstep) * 1024) = hv;
    }
    // prefetch next step's xg (consumed after next barrier)
    uint2 xn[4];
    if (ti + 1 < T) {
      #pragma unroll
      for (int j = 0; j < 4; ++j)
        xn[j] = *(const uint2*)(xb + (size_t)(t + tstep) * 2048 + j * 16);
    }
    // MFMA: acc[j] = Whh-tile(w*4+j) x h ; weights from LDS (w<8) or L2 stream
    f32x4 acc[4];
    #pragma unroll
    for (int j = 0; j < 4; ++j) acc[j] = f32x4{0.f, 0.f, 0.f, 0.f};
    if (w < 8) {
      const long* wl = wlds + w * 2048 + lane;
      #pragma unroll
      for (int kf = 0; kf < 8; ++kf) {
        const long bf = hb[cur][kf * 64 + q * 16 + n];
        #pragma unroll
        for (int j = 0; j < 4; ++j)
          acc[j] = __builtin_amdgcn_mfma_f32_16x16x32_fp8_fp8(wl[(j * 8 + kf) * 64], bf, acc[j], 0, 0, 0);
      }
    } else {
      const uint2* wg = Wp + (size_t)(w * 32) * 64 + lane;
      #pragma unroll
      for (int kf = 0; kf < 8; ++kf) {
        const long bf = hb[cur][kf * 64 + q * 16 + n];
        #pragma unroll
        for (int j = 0; j < 4; ++j) {
          const long a = __builtin_bit_cast(long, wg[(size_t)(j * 8 + kf) * 64]);
          acc[j] = __builtin_amdgcn_mfma_f32_16x16x32_fp8_fp8(a, bf, acc[j], 0, 0, 0);
        }
      }
    }
    // cell update (R9 form): lane owns (unit u, sample n) fully
    unsigned char* hw = (unsigned char*)&hb[cur ^ 1][0];
    #pragma unroll
    for (int j = 0; j < 4; ++j) {
      const int u = w * 16 + j * 4 + q;
      const float gi = acc[j][0] + lo16(xv[j].x);
      const float gf = acc[j][1] + hi16(xv[j].x);
      const float gg = acc[j][2] + lo16(xv[j].y);
      const float go = acc[j][3] + hi16(xv[j].y);
      c[j] = sigm(gf) * c[j] + sigm(gi) * tanh_f(gg);
      const float h = sigm(go) * tanh_f(c[j]);
      hw[(u >> 3) * 128 + n * 8 + (u & 7)] = f2e4m3(h);
      hout[cur ^ 1][n][u] = f2b(h);
    }
    __syncthreads();                   // new h visible; old buffers free
    #pragma unroll
    for (int j = 0; j < 4; ++j) xv[j] = xn[j];
    t += tstep;
    cur ^= 1;
  }
  // epilogue: store last step's h
  const uint2 hv = *(const uint2*)&hout[cur][w][lane * 4];
  *(uint2*)(orow + (size_t)(t - tstep) * 1024) = hv;
}

// ---------- classifier layer 2 ----------
__global__ __launch_bounds__(256) void cls2_kernel(const unsigned short* __restrict__ h1,
                                                   const unsigned short* __restrict__ w2,
                                                   const float* __restrict__ b2,
                                                   float* __restrict__ logits, int M) {
  int idx = blockIdx.x * 256 + threadIdx.x;
  int row = idx >> 4, n = idx & 15;
  if (row >= M || n >= 15) return;
  const unsigned* hp = (const unsigned*)(h1 + (size_t)row * 512);
  const unsigned* wp = (const unsigned*)(w2 + (size_t)n * 512);
  float acc = 0.f;
  #pragma unroll 8
  for (int k = 0; k < 256; ++k) {
    unsigned uh = hp[k], uw = wp[k];
    acc = fmaf(lo16(uh), lo16(uw), acc);
    acc = fmaf(hi16(uh), hi16(uw), acc);
  }
  logits[(size_t)row * 16 + n] = acc + b2[n];
}

// ---------- CRF ----------
__global__ __launch_bounds__(256) void crf_num(const float* __restrict__ logits,
                                               const int* __restrict__ tags,
                                               const float* __restrict__ start,
                                               const float* __restrict__ end,
                                               const float* __restrict__ trans,
                                               float* __restrict__ numout, int T) {
  int b = blockIdx.x, tid = threadIdx.x;
  const int* tg = tags + (size_t)b * T;
  float s = 0.f;
  for (int t = tid; t < T; t += 256) {
    int cur = tg[t];
    s += logits[((size_t)b * T + t) * 16 + cur];
    if (t > 0) s += trans[tg[t - 1] * 15 + cur];
  }
  #pragma unroll
  for (int off = 32; off > 0; off >>= 1) s += __shfl_down(s, off, 64);
  __shared__ float red[4];
  if ((tid & 63) == 0) red[tid >> 6] = s;
  __syncthreads();
  if (tid == 0)
    numout[b] = red[0] + red[1] + red[2] + red[3] + start[tg[0]] + end[tg[T - 1]];
}

__global__ void crf_denom(const float* __restrict__ logits, const float* __restrict__ start,
                          const float* __restrict__ end, const float* __restrict__ trans,
                          float* __restrict__ denout, int T) {
  int b = blockIdx.x;
  int lane = threadIdx.x;
  int kp = lane < 15 ? lane : 0;
  float tcol[15];
  #pragma unroll
  for (int k = 0; k < 15; ++k) tcol[k] = trans[k * 15 + kp];
  float score = start[kp] + logits[((size_t)b * T) * 16 + kp];
  for (int t = 1; t < T; ++t) {
    float e = logits[((size_t)b * T + t) * 16 + kp];
    float s[15], m = -3.4e38f;
    #pragma unroll
    for (int k = 0; k < 15; ++k) {
      s[k] = __shfl(score, k, 64) + tcol[k];
      m = fmaxf(m, s[k]);
    }
    float sum = 0.f;
    #pragma unroll
    for (int k = 0; k < 15; ++k) sum += __expf(s[k] - m);
    score = e + m + __logf(sum);
  }
  float x = score + end[kp];
  float m = -3.4e38f;
  #pragma unroll
  for (int k = 0; k < 15; ++k) m = fmaxf(m, __shfl(x, k, 64));
  float sum = 0.f;
  #pragma unroll
  for (int k = 0; k < 15; ++k) sum += __expf(__shfl(x, k, 64) - m);
  if (lane == 0) denout[b] = m + __logf(sum);
}

__global__ void crf_final(const float* __restrict__ num, const float* __restrict__ den,
                          float* __restrict__ out) {
  int l = threadIdx.x;
  float v = den[l] - num[l];
  #pragma unroll
  for (int off = 32; off > 0; off >>= 1) v += __shfl_xor(v, off, 64);
  if (l == 0) out[0] = v * (1.f / 64.f);
}

// ---------- host ----------
extern "C" void kernel_launch(void* const* d_in, const int* in_sizes, int n_in,
                              void* d_out, int out_size, void* d_ws, size_t ws_size,
                              hipStream_t stream) {
  const int B = 64, T = 512, M = B * T;   // 32768
  const float* we   = (const float*)d_in[1];
  const int*   cid  = (const int*)d_in[0];
  const int*   tags = (const int*)d_in[2];
  const float* etab = (const float*)d_in[3];

  char* ws = (char*)d_ws;
  size_t off = 0;
  auto alloc = [&](size_t bytes) -> char* {
    char* p = ws + off;
    off += (bytes + 255) & ~(size_t)255;
    return p;
  };
  // small, permanent
  unsigned short* wih_c0 = (unsigned short*)alloc((size_t)2048 * 128 * 2);
  unsigned short* wih_c1 = (unsigned short*)alloc((size_t)2048 * 512 * 2);
  unsigned short* wih_w0 = (unsigned short*)alloc((size_t)2048 * 768 * 2);
  unsigned short* wih_w1 = (unsigned short*)alloc((size_t)2048 * 512 * 2);
  unsigned short* cls1b  = (unsigned short*)alloc((size_t)512 * 1024 * 2);
  unsigned short* cls2b  = (unsigned short*)alloc((size_t)15 * 512 * 2);
  uint2* whh_c0 = (uint2*)alloc((size_t)65536 * 8);
  uint2* whh_c1 = (uint2*)alloc((size_t)65536 * 8);
  uint2* whh_w0 = (uint2*)alloc((size_t)65536 * 8);
  uint2* whh_w1 = (uint2*)alloc((size_t)65536 * 8);
  float* bs_c0 = (float*)alloc(2048 * 4);
  float* bs_c1 = (float*)alloc(2048 * 4);
  float* bs_w0 = (float*)alloc(2048 * 4);
  float* bs_w1 = (float*)alloc(2048 * 4);
  float* numb = (float*)alloc(64 * 4);
  float* denb = (float*)alloc(64 * 4);
  // big
  unsigned short* comb = (unsigned short*)alloc((size_t)M * 1024 * 2);   // 64 MB
  unsigned short* xg_c = (unsigned short*)alloc((size_t)M * 2048 * 2);   // 128 MB
  const size_t xgw_bytes = (size_t)M * 2048 * 2;
  const bool fused = (off + xgw_bytes) <= ws_size;
  unsigned short* xg_w;
  unsigned short* ce_b;
  unsigned short* we_b;
  if (fused) {
    xg_w = (unsigned short*)alloc(xgw_bytes);
    ce_b = xg_w;          // consumed by g_c0 before g_w0 overwrites xg_w
    we_b = comb;          // consumed by g_w0 before lstm0 writes comb
  } else {
    xg_w = xg_c;
    ce_b = (unsigned short*)alloc((size_t)M * 128 * 2);
    we_b = (unsigned short*)alloc((size_t)M * 768 * 2);
  }
  unsigned short* h1 = xg_c;                        // free after level-1 lstm
  float* logits = (float*)(xg_c + (size_t)24 * 1024 * 1024);   // +48MB into xg_c

  // ---- prep ----
  cvt_bf16<<<1024, 256, 0, stream>>>((const float*)d_in[4],  wih_c0, 2048 * 128);
  cvt_bf16<<<1024, 256, 0, stream>>>((const float*)d_in[8],  wih_c1, 2048 * 512);
  cvt_bf16<<<1024, 256, 0, stream>>>((const float*)d_in[12], wih_w0, 2048 * 768);
  cvt_bf16<<<1024, 256, 0, stream>>>((const float*)d_in[16], wih_w1, 2048 * 512);
  cvt_bf16<<<1024, 256, 0, stream>>>((const float*)d_in[20], cls1b, 512 * 1024);
  cvt_bf16<<<64, 256, 0, stream>>>((const float*)d_in[22], cls2b, 15 * 512);
  cvt_bf16<<<4096, 256, 0, stream>>>(we, we_b, M * 768);
  whh_pack<<<256, 256, 0, stream>>>((const float*)d_in[5],  whh_c0);
  whh_pack<<<256, 256, 0, stream>>>((const float*)d_in[9],  whh_c1);
  whh_pack<<<256, 256, 0, stream>>>((const float*)d_in[13], whh_w0);
  whh_pack<<<256, 256, 0, stream>>>((const float*)d_in[17], whh_w1);
  bias_sum<<<8, 256, 0, stream>>>((const float*)d_in[6],  (const float*)d_in[7],  bs_c0, 2048);
  bias_sum<<<8, 256, 0, stream>>>((const float*)d_in[10], (const float*)d_in[11], bs_c1, 2048);
  bias_sum<<<8, 256, 0, stream>>>((const float*)d_in[14], (const float*)d_in[15], bs_w0, 2048);
  bias_sum<<<8, 256, 0, stream>>>((const float*)d_in[18], (const float*)d_in[19], bs_w1, 2048);
  embed_gather<<<8192, 256, 0, stream>>>(cid, etab, ce_b, M * 128);

  const int G2048 = (M >> 7) * (2048 >> 7);   // 4096
  const int G512  = (M >> 7) * (512 >> 7);    // 1024
  if (fused) {
    gemm_lds<0, 1><<<G2048, 256, 0, stream>>>(ce_b, 128, wih_c0, bs_c0, xg_c, M, 2048, 128);
    gemm_lds<0, 1><<<G2048, 256, 0, stream>>>(we_b, 768, wih_w0, bs_w0, xg_w, M, 2048, 768);
    lstm_mfma<<<16, 1024, 0, stream>>>(whh_c0, xg_c, comb, 0,
                                       whh_w0, xg_w, comb, 512, T);
    gemm_lds<0, 1><<<G2048, 256, 0, stream>>>(comb, 1024, wih_c1, bs_c1, xg_c, M, 2048, 512);
    gemm_lds<0, 1><<<G2048, 256, 0, stream>>>(comb + 512, 1024, wih_w1, bs_w1, xg_w, M, 2048, 512);
    lstm_mfma<<<16, 1024, 0, stream>>>(whh_c1, xg_c, comb, 0,
                                       whh_w1, xg_w, comb, 512, T);
  } else {
    gemm_lds<0, 1><<<G2048, 256, 0, stream>>>(ce_b, 128, wih_c0, bs_c0, xg_c, M, 2048, 128);
    lstm_mfma<<<8, 1024, 0, stream>>>(whh_c0, xg_c, comb, 0, whh_c0, xg_c, comb, 0, T);
    gemm_lds<0, 1><<<G2048, 256, 0, stream>>>(comb, 1024, wih_c1, bs_c1, xg_c, M, 2048, 512);
    lstm_mfma<<<8, 1024, 0, stream>>>(whh_c1, xg_c, comb, 0, whh_c1, xg_c, comb, 0, T);
    gemm_lds<0, 1><<<G2048, 256, 0, stream>>>(we_b, 768, wih_w0, bs_w0, xg_c, M, 2048, 768);
    lstm_mfma<<<8, 1024, 0, stream>>>(whh_w0, xg_c, comb, 512, whh_w0, xg_c, comb, 512, T);
    gemm_lds<0, 1><<<G2048, 256, 0, stream>>>(comb + 512, 1024, wih_w1, bs_w1, xg_c, M, 2048, 512);
    lstm_mfma<<<8, 1024, 0, stream>>>(whh_w1, xg_c, comb, 512, whh_w1, xg_c, comb, 512, T);
  }
  // ---- classifier ----
  gemm_lds<1, 0><<<G512, 256, 0, stream>>>(comb, 1024, cls1b, (const float*)d_in[21], h1, M, 512, 1024);
  cls2_kernel<<<2048, 256, 0, stream>>>(h1, cls2b, (const float*)d_in[23], logits, M);
  // ---- CRF ----
  crf_num<<<64, 256, 0, stream>>>(logits, tags, (const float*)d_in[24], (const float*)d_in[25],
                                  (const float*)d_in[26], numb, T);
  crf_denom<<<64, 64, 0, stream>>>(logits, (const float*)d_in[24], (const float*)d_in[25],
                                   (const float*)d_in[26], denb, T);
  crf_final<<<1, 64, 0, stream>>>(numb, denb, (float*)d_out);
}

// Round 13
// 5614.142 us; speedup vs baseline: 1.3085x; 1.3085x over previous
//
#include <hip/hip_runtime.h>

#define DEVI __device__ __forceinline__

typedef __attribute__((ext_vector_type(8))) __bf16 bf16x8;
typedef __attribute__((ext_vector_type(4))) float f32x4;

// ---------- scalar helpers ----------
DEVI unsigned short f2b(float f) {           // f32 -> bf16 (RNE)
  unsigned u = __float_as_uint(f);
  u = u + 0x7fffu + ((u >> 16) & 1u);
  return (unsigned short)(u >> 16);
}
DEVI float lo16(unsigned u) { return __uint_as_float(u << 16); }
DEVI float hi16(unsigned u) { return __uint_as_float(u & 0xffff0000u); }
#if __has_builtin(__builtin_amdgcn_rcpf)
DEVI float rcpf(float x) { return __builtin_amdgcn_rcpf(x); }
#else
DEVI float rcpf(float x) { return 1.f / x; }
#endif
DEVI float sigm(float x) { return rcpf(1.f + __expf(-x)); }
DEVI float tanh_f(float x) { return fmaf(2.f, rcpf(1.f + __expf(-2.f * x)), -1.f); }

// ---------- fp8 e4m3fn encode ----------
#if __has_builtin(__builtin_amdgcn_cvt_pk_fp8_f32)
DEVI unsigned char f2e4m3(float f) {
  return (unsigned char)(__builtin_amdgcn_cvt_pk_fp8_f32(f, f, 0, false) & 0xff);
}
#else
DEVI unsigned char f2e4m3(float f) {   // software RNE e4m3fn
  unsigned u = __float_as_uint(f);
  unsigned s = (u >> 31) << 7;
  float a = fabsf(f);
  if (a >= 448.f) return (unsigned char)(s | 0x7e);
  if (a < 0.015625f) {                 // denorm, unit 2^-9
    int m = (int)rintf(a * 512.f);
    if (m >= 8) return (unsigned char)(s | 0x08);
    return (unsigned char)(s | m);
  }
  unsigned ur = u + 0x7FFFF + ((u >> 20) & 1);   // RNE at mantissa bit 20
  int e8 = (int)((ur >> 23) & 255) - 127 + 7;
  unsigned m3 = (ur >> 20) & 7;
  if (e8 > 15 || (e8 == 15 && m3 > 6)) return (unsigned char)(s | 0x7e);
  if (e8 <= 0) return (unsigned char)s;
  return (unsigned char)(s | (e8 << 3) | m3);
}
#endif

// ---------- prep kernels ----------
__global__ void cvt_bf16(const float* __restrict__ in, unsigned short* __restrict__ out, int n) {
  for (int i = blockIdx.x * blockDim.x + threadIdx.x; i < n; i += gridDim.x * blockDim.x)
    out[i] = f2b(in[i]);
}

// Whh (2,1024,256) f32 -> fp8 MFMA-A-fragment order:
// uint2 index = ((d*64 + mt)*8 + kf)*64 + lane; bytes j=0..7:
//   row = mt*16 + (lane&15); unit = row>>2; gate = row&3;
//   k = kf*32 + (lane>>4)*8 + j;  src = W[d][gate*256 + unit][k]
__global__ void whh_pack(const float* __restrict__ W, uint2* __restrict__ out) {
  int idx = blockIdx.x * blockDim.x + threadIdx.x;   // 65536 total
  if (idx >= 65536) return;
  int d = idx >> 15, rem = idx & 32767;
  int mt = rem >> 9, kf = (rem >> 6) & 7, lane = rem & 63;
  int row = mt * 16 + (lane & 15);
  int unit = row >> 2, gate = row & 3;
  int kb = kf * 32 + (lane >> 4) * 8;
  const float* w = W + (((size_t)d * 1024 + gate * 256 + unit) * 256 + kb);
  unsigned lo = 0, hi = 0;
  #pragma unroll
  for (int j = 0; j < 4; ++j) lo |= (unsigned)f2e4m3(w[j]) << (8 * j);
  #pragma unroll
  for (int j = 0; j < 4; ++j) hi |= (unsigned)f2e4m3(w[4 + j]) << (8 * j);
  out[idx] = make_uint2(lo, hi);
}

__global__ void bias_sum(const float* __restrict__ a, const float* __restrict__ b,
                         float* __restrict__ o, int n) {
  int i = blockIdx.x * blockDim.x + threadIdx.x;
  if (i < n) o[i] = a[i] + b[i];
}

__global__ void embed_gather(const int* __restrict__ ids, const float* __restrict__ tab,
                             unsigned short* __restrict__ out, int total) {
  for (int i = blockIdx.x * blockDim.x + threadIdx.x; i < total; i += gridDim.x * blockDim.x) {
    int bt = i >> 7, c = i & 127;
    out[i] = f2b(tab[(size_t)ids[bt] * 128 + c]);
  }
}

// ---------- GEMM (LDS-staged): C[M,N] = act(A[M,K](lda,bf16) @ W[N,K]^T + bias) -> bf16
// 128x128 tile, 256 thr (4 waves), K-step 32. (R11, measured good.)
template <int ACT, int PERM>
__global__ __launch_bounds__(256) void gemm_lds(const unsigned short* __restrict__ A, int lda,
                                                const unsigned short* __restrict__ W,
                                                const float* __restrict__ bias,
                                                unsigned short* __restrict__ C,
                                                int M, int N, int K) {
  const int ntiles = N >> 7;
  const int mt = blockIdx.x / ntiles;
  const int nt = blockIdx.x - mt * ntiles;
  const int m0 = mt << 7, n0 = nt << 7;
  const int tid = threadIdx.x;
  const int w = tid >> 6, lane = tid & 63, r = lane & 15, q = lane >> 4;
  __shared__ unsigned short lsA[4096], lsB[4096];
  f32x4 acc[16];
  #pragma unroll
  for (int i = 0; i < 16; ++i) acc[i] = f32x4{0.f, 0.f, 0.f, 0.f};

  const int srow = tid >> 2, sq = tid & 3;
  const int s0 = (srow << 2) | (sq ^ (srow & 3) ^ ((srow >> 2) & 3));
  const unsigned short* gA = A + (size_t)(m0 + srow) * lda + sq * 8;
  const unsigned short* gB = W + (size_t)(n0 + srow) * K + sq * 8;
  const size_t gAs = (size_t)64 * lda, gBs = (size_t)64 * K;
  const int sw = q ^ (r & 3) ^ ((r >> 2) & 3);

  for (int k0 = 0; k0 < K; k0 += 32) {
    uint4 va0 = *(const uint4*)(gA + k0);
    uint4 va1 = *(const uint4*)(gA + gAs + k0);
    uint4 vb0 = *(const uint4*)(gB + k0);
    uint4 vb1 = *(const uint4*)(gB + gBs + k0);
    *(uint4*)(lsA + s0 * 8) = va0;
    *(uint4*)(lsA + s0 * 8 + 2048) = va1;
    *(uint4*)(lsB + s0 * 8) = vb0;
    *(uint4*)(lsB + s0 * 8 + 2048) = vb1;
    __syncthreads();
    const bf16x8 a0 = *(const bf16x8*)(const void*)(lsA + ((w * 32 + r) * 4 + sw) * 8);
    const bf16x8 a1 = *(const bf16x8*)(const void*)(lsA + ((w * 32 + 16 + r) * 4 + sw) * 8);
    #pragma unroll
    for (int nf = 0; nf < 8; ++nf) {
      const bf16x8 b = *(const bf16x8*)(const void*)(lsB + ((nf * 16 + r) * 4 + sw) * 8);
      acc[nf]     = __builtin_amdgcn_mfma_f32_16x16x32_bf16(a0, b, acc[nf], 0, 0, 0);
      acc[8 + nf] = __builtin_amdgcn_mfma_f32_16x16x32_bf16(a1, b, acc[8 + nf], 0, 0, 0);
    }
    __syncthreads();
  }
  #pragma unroll
  for (int mf = 0; mf < 2; ++mf) {
    const int rbase = m0 + w * 32 + mf * 16 + q * 4;
    #pragma unroll
    for (int nf = 0; nf < 8; ++nf) {
      const f32x4 a = acc[mf * 8 + nf];
      const int col = n0 + nf * 16 + r;
      const float bv = bias[col];
      int oc = col;
      if constexpr (PERM) oc = (col & 1024) | ((col & 255) << 2) | ((col >> 8) & 3);
      #pragma unroll
      for (int i = 0; i < 4; ++i) {
        float v = a[i] + bv;
        if constexpr (ACT) v = fmaxf(v, 0.f);
        C[(size_t)(rbase + i) * N + oc] = f2b(v);
      }
    }
  }
}

// ---------- LSTM recurrence via MFMA fp8 (R10 form: pure L2 stream) ----------
__global__ __launch_bounds__(1024, 4) void lstm_mfma(
    const uint2* __restrict__ W0, const unsigned short* __restrict__ x0,
    unsigned short* __restrict__ o0, int oo0,
    const uint2* __restrict__ W1, const unsigned short* __restrict__ x1,
    unsigned short* __restrict__ o1, int oo1, int T) {
  const int bid = blockIdx.x;
  const int sg = bid & 3, dir = (bid >> 2) & 1, grp = bid >> 3;
  const uint2* __restrict__ Wp = (grp ? W1 : W0) + (size_t)dir * 32768;
  const unsigned short* __restrict__ xg = grp ? x1 : x0;
  unsigned short* __restrict__ out = grp ? o1 : o0;
  const int outOff = grp ? oo1 : oo0;

  const int tid = threadIdx.x;
  const int w = tid >> 6, lane = tid & 63, q = lane >> 4, n = lane & 15;
  const int b = sg * 16 + n;

  __shared__ long hb[2][512];
  __shared__ unsigned short hout[2][16][264];
  hb[0][tid & 511] = 0;
  hb[1][tid & 511] = 0;

  float c[4] = {0.f, 0.f, 0.f, 0.f};
  const unsigned short* xb = xg + ((size_t)b * T) * 2048 + dir * 1024 + (w * 16 + q) * 4;
  const uint2* wbase = Wp + (size_t)(w * 32) * 64 + lane;
  unsigned short* orow = out + ((size_t)(sg * 16 + w) * T) * 1024 + outOff + dir * 256 + lane * 4;

  const int tstep = dir ? -1 : 1;
  int t = dir ? T - 1 : 0;
  uint2 xv[4];
  #pragma unroll
  for (int j = 0; j < 4; ++j)
    xv[j] = *(const uint2*)(xb + (size_t)t * 2048 + j * 16);
  __syncthreads();

  int cur = 0;
  for (int ti = 0; ti < T; ++ti) {
    if (ti) {
      const uint2 hv = *(const uint2*)&hout[cur][w][lane * 4];
      *(uint2*)(orow + (size_t)(t - tstep) * 1024) = hv;
    }
    uint2 xn[4];
    if (ti + 1 < T) {
      #pragma unroll
      for (int j = 0; j < 4; ++j)
        xn[j] = *(const uint2*)(xb + (size_t)(t + tstep) * 2048 + j * 16);
    }
    f32x4 acc[4];
    #pragma unroll
    for (int j = 0; j < 4; ++j) acc[j] = f32x4{0.f, 0.f, 0.f, 0.f};
    #pragma unroll
    for (int kf = 0; kf < 8; ++kf) {
      const long bf = hb[cur][kf * 64 + q * 16 + n];
      #pragma unroll
      for (int j = 0; j < 4; ++j) {
        const long a = __builtin_bit_cast(long, wbase[(size_t)(j * 8 + kf) * 64]);
        acc[j] = __builtin_amdgcn_mfma_f32_16x16x32_fp8_fp8(a, bf, acc[j], 0, 0, 0);
      }
    }
    unsigned char* hw = (unsigned char*)&hb[cur ^ 1][0];
    #pragma unroll
    for (int j = 0; j < 4; ++j) {
      const int u = w * 16 + j * 4 + q;
      const float gi = acc[j][0] + lo16(xv[j].x);
      const float gf = acc[j][1] + hi16(xv[j].x);
      const float gg = acc[j][2] + lo16(xv[j].y);
      const float go = acc[j][3] + hi16(xv[j].y);
      c[j] = sigm(gf) * c[j] + sigm(gi) * tanh_f(gg);
      const float h = sigm(go) * tanh_f(c[j]);
      hw[(u >> 3) * 128 + n * 8 + (u & 7)] = f2e4m3(h);
      hout[cur ^ 1][n][u] = f2b(h);
    }
    __syncthreads();
    #pragma unroll
    for (int j = 0; j < 4; ++j) xv[j] = xn[j];
    t += tstep;
    cur ^= 1;
  }
  const uint2 hv = *(const uint2*)&hout[cur][w][lane * 4];
  *(uint2*)(orow + (size_t)(t - tstep) * 1024) = hv;
}

// ---------- LSTM variant: half the weights pinned in AGPRs via asm "a" constraint ----
// kf=0..3 weights live in AGPRs (32 a-regs; loaded once, used only by asm MFMA ->
// compiler cannot rematerialize). kf=4..7 streamed from L2 via builtins.
// MFMA ordering per acc chain: builtin(4,5,6) -> asm(0..3) -> builtin(7), so every
// VALU<->MFMA boundary is a compiler-managed builtin (hazard-safe); asm MFMAs only
// neighbor other MFMAs (same-acc chaining needs no waits).
__global__ __launch_bounds__(1024, 4) void lstm_mfma_ag(
    const uint2* __restrict__ W0, const unsigned short* __restrict__ x0,
    unsigned short* __restrict__ o0, int oo0,
    const uint2* __restrict__ W1, const unsigned short* __restrict__ x1,
    unsigned short* __restrict__ o1, int oo1, int T) {
  const int bid = blockIdx.x;
  const int sg = bid & 3, dir = (bid >> 2) & 1, grp = bid >> 3;
  const uint2* __restrict__ Wp = (grp ? W1 : W0) + (size_t)dir * 32768;
  const unsigned short* __restrict__ xg = grp ? x1 : x0;
  unsigned short* __restrict__ out = grp ? o1 : o0;
  const int outOff = grp ? oo1 : oo0;

  const int tid = threadIdx.x;
  const int w = tid >> 6, lane = tid & 63, q = lane >> 4, n = lane & 15;
  const int b = sg * 16 + n;

  __shared__ long hb[2][512];
  __shared__ unsigned short hout[2][16][264];
  hb[0][tid & 511] = 0;
  hb[1][tid & 511] = 0;

  // preload kf=0..3 slices (8 KB/wave) -> pinned to AGPRs by asm "a" use below
  long wa[16];
  {
    const uint2* ap = Wp + (size_t)(w * 32) * 64 + lane;
    #pragma unroll
    for (int j = 0; j < 4; ++j)
      #pragma unroll
      for (int kf = 0; kf < 4; ++kf)
        wa[j * 4 + kf] = __builtin_bit_cast(long, ap[(size_t)(j * 8 + kf) * 64]);
  }

  float c[4] = {0.f, 0.f, 0.f, 0.f};
  const unsigned short* xb = xg + ((size_t)b * T) * 2048 + dir * 1024 + (w * 16 + q) * 4;
  const uint2* wbase = Wp + (size_t)(w * 32) * 64 + lane;
  unsigned short* orow = out + ((size_t)(sg * 16 + w) * T) * 1024 + outOff + dir * 256 + lane * 4;

  const int tstep = dir ? -1 : 1;
  int t = dir ? T - 1 : 0;
  uint2 xv[4];
  #pragma unroll
  for (int j = 0; j < 4; ++j)
    xv[j] = *(const uint2*)(xb + (size_t)t * 2048 + j * 16);
  __syncthreads();

  int cur = 0;
  for (int ti = 0; ti < T; ++ti) {
    if (ti) {
      const uint2 hv = *(const uint2*)&hout[cur][w][lane * 4];
      *(uint2*)(orow + (size_t)(t - tstep) * 1024) = hv;
    }
    uint2 xn[4];
    if (ti + 1 < T) {
      #pragma unroll
      for (int j = 0; j < 4; ++j)
        xn[j] = *(const uint2*)(xb + (size_t)(t + tstep) * 2048 + j * 16);
    }
    f32x4 acc[4];
    #pragma unroll
    for (int j = 0; j < 4; ++j) acc[j] = f32x4{0.f, 0.f, 0.f, 0.f};
    // streamed kf=4..6 (builtin: handles zero-init entry hazards)
    #pragma unroll
    for (int kf = 4; kf < 7; ++kf) {
      const long bf = hb[cur][kf * 64 + q * 16 + n];
      #pragma unroll
      for (int j = 0; j < 4; ++j) {
        const long a = __builtin_bit_cast(long, wbase[(size_t)(j * 8 + kf) * 64]);
        acc[j] = __builtin_amdgcn_mfma_f32_16x16x32_fp8_fp8(a, bf, acc[j], 0, 0, 0);
      }
    }
    // AGPR-resident kf=0..3 (asm; A operand from AGPR pair)
    #pragma unroll
    for (int kf = 0; kf < 4; ++kf) {
      const long bf = hb[cur][kf * 64 + q * 16 + n];
      #pragma unroll
      for (int j = 0; j < 4; ++j)
        asm volatile("v_mfma_f32_16x16x32_fp8_fp8 %0, %1, %2, %0"
                     : "+v"(acc[j]) : "a"(wa[j * 4 + kf]), "v"(bf));
    }
    // streamed kf=7 last (builtin: handles MFMA->VALU exit hazard)
    {
      const long bf = hb[cur][7 * 64 + q * 16 + n];
      #pragma unroll
      for (int j = 0; j < 4; ++j) {
        const long a = __builtin_bit_cast(long, wbase[(size_t)(j * 8 + 7) * 64]);
        acc[j] = __builtin_amdgcn_mfma_f32_16x16x32_fp8_fp8(a, bf, acc[j], 0, 0, 0);
      }
    }
    unsigned char* hw = (unsigned char*)&hb[cur ^ 1][0];
    #pragma unroll
    for (int j = 0; j < 4; ++j) {
      const int u = w * 16 + j * 4 + q;
      const float gi = acc[j][0] + lo16(xv[j].x);
      const float gf = acc[j][1] + hi16(xv[j].x);
      const float gg = acc[j][2] + lo16(xv[j].y);
      const float go = acc[j][3] + hi16(xv[j].y);
      c[j] = sigm(gf) * c[j] + sigm(gi) * tanh_f(gg);
      const float h = sigm(go) * tanh_f(c[j]);
      hw[(u >> 3) * 128 + n * 8 + (u & 7)] = f2e4m3(h);
      hout[cur ^ 1][n][u] = f2b(h);
    }
    __syncthreads();
    #pragma unroll
    for (int j = 0; j < 4; ++j) xv[j] = xn[j];
    t += tstep;
    cur ^= 1;
  }
  const uint2 hv = *(const uint2*)&hout[cur][w][lane * 4];
  *(uint2*)(orow + (size_t)(t - tstep) * 1024) = hv;
}

// ---------- classifier layer 2 ----------
__global__ __launch_bounds__(256) void cls2_kernel(const unsigned short* __restrict__ h1,
                                                   const unsigned short* __restrict__ w2,
                                                   const float* __restrict__ b2,
                                                   float* __restrict__ logits, int M) {
  int idx = blockIdx.x * 256 + threadIdx.x;
  int row = idx >> 4, n = idx & 15;
  if (row >= M || n >= 15) return;
  const unsigned* hp = (const unsigned*)(h1 + (size_t)row * 512);
  const unsigned* wp = (const unsigned*)(w2 + (size_t)n * 512);
  float acc = 0.f;
  #pragma unroll 8
  for (int k = 0; k < 256; ++k) {
    unsigned uh = hp[k], uw = wp[k];
    acc = fmaf(lo16(uh), lo16(uw), acc);
    acc = fmaf(hi16(uh), hi16(uw), acc);
  }
  logits[(size_t)row * 16 + n] = acc + b2[n];
}

// ---------- CRF ----------
__global__ __launch_bounds__(256) void crf_num(const float* __restrict__ logits,
                                               const int* __restrict__ tags,
                                               const float* __restrict__ start,
                                               const float* __restrict__ end,
                                               const float* __restrict__ trans,
                                               float* __restrict__ numout, int T) {
  int b = blockIdx.x, tid = threadIdx.x;
  const int* tg = tags + (size_t)b * T;
  float s = 0.f;
  for (int t = tid; t < T; t += 256) {
    int cur = tg[t];
    s += logits[((size_t)b * T + t) * 16 + cur];
    if (t > 0) s += trans[tg[t - 1] * 15 + cur];
  }
  #pragma unroll
  for (int off = 32; off > 0; off >>= 1) s += __shfl_down(s, off, 64);
  __shared__ float red[4];
  if ((tid & 63) == 0) red[tid >> 6] = s;
  __syncthreads();
  if (tid == 0)
    numout[b] = red[0] + red[1] + red[2] + red[3] + start[tg[0]] + end[tg[T - 1]];
}

__global__ void crf_denom(const float* __restrict__ logits, const float* __restrict__ start,
                          const float* __restrict__ end, const float* __restrict__ trans,
                          float* __restrict__ denout, int T) {
  int b = blockIdx.x;
  int lane = threadIdx.x;
  int kp = lane < 15 ? lane : 0;
  float tcol[15];
  #pragma unroll
  for (int k = 0; k < 15; ++k) tcol[k] = trans[k * 15 + kp];
  float score = start[kp] + logits[((size_t)b * T) * 16 + kp];
  for (int t = 1; t < T; ++t) {
    float e = logits[((size_t)b * T + t) * 16 + kp];
    float s[15], m = -3.4e38f;
    #pragma unroll
    for (int k = 0; k < 15; ++k) {
      s[k] = __shfl(score, k, 64) + tcol[k];
      m = fmaxf(m, s[k]);
    }
    float sum = 0.f;
    #pragma unroll
    for (int k = 0; k < 15; ++k) sum += __expf(s[k] - m);
    score = e + m + __logf(sum);
  }
  float x = score + end[kp];
  float m = -3.4e38f;
  #pragma unroll
  for (int k = 0; k < 15; ++k) m = fmaxf(m, __shfl(x, k, 64));
  float sum = 0.f;
  #pragma unroll
  for (int k = 0; k < 15; ++k) sum += __expf(__shfl(x, k, 64) - m);
  if (lane == 0) denout[b] = m + __logf(sum);
}

__global__ void crf_final(const float* __restrict__ num, const float* __restrict__ den,
                          float* __restrict__ out) {
  int l = threadIdx.x;
  float v = den[l] - num[l];
  #pragma unroll
  for (int off = 32; off > 0; off >>= 1) v += __shfl_xor(v, off, 64);
  if (l == 0) out[0] = v * (1.f / 64.f);
}

// ---------- host ----------
extern "C" void kernel_launch(void* const* d_in, const int* in_sizes, int n_in,
                              void* d_out, int out_size, void* d_ws, size_t ws_size,
                              hipStream_t stream) {
  const int B = 64, T = 512, M = B * T;   // 32768
  const float* we   = (const float*)d_in[1];
  const int*   cid  = (const int*)d_in[0];
  const int*   tags = (const int*)d_in[2];
  const float* etab = (const float*)d_in[3];

  char* ws = (char*)d_ws;
  size_t off = 0;
  auto alloc = [&](size_t bytes) -> char* {
    char* p = ws + off;
    off += (bytes + 255) & ~(size_t)255;
    return p;
  };
  // small, permanent
  unsigned short* wih_c0 = (unsigned short*)alloc((size_t)2048 * 128 * 2);
  unsigned short* wih_c1 = (unsigned short*)alloc((size_t)2048 * 512 * 2);
  unsigned short* wih_w0 = (unsigned short*)alloc((size_t)2048 * 768 * 2);
  unsigned short* wih_w1 = (unsigned short*)alloc((size_t)2048 * 512 * 2);
  unsigned short* cls1b  = (unsigned short*)alloc((size_t)512 * 1024 * 2);
  unsigned short* cls2b  = (unsigned short*)alloc((size_t)15 * 512 * 2);
  uint2* whh_c0 = (uint2*)alloc((size_t)65536 * 8);
  uint2* whh_c1 = (uint2*)alloc((size_t)65536 * 8);
  uint2* whh_w0 = (uint2*)alloc((size_t)65536 * 8);
  uint2* whh_w1 = (uint2*)alloc((size_t)65536 * 8);
  float* bs_c0 = (float*)alloc(2048 * 4);
  float* bs_c1 = (float*)alloc(2048 * 4);
  float* bs_w0 = (float*)alloc(2048 * 4);
  float* bs_w1 = (float*)alloc(2048 * 4);
  float* numb = (float*)alloc(64 * 4);
  float* denb = (float*)alloc(64 * 4);
  // big
  unsigned short* comb = (unsigned short*)alloc((size_t)M * 1024 * 2);   // 64 MB
  unsigned short* xg_c = (unsigned short*)alloc((size_t)M * 2048 * 2);   // 128 MB
  const size_t xgw_bytes = (size_t)M * 2048 * 2;
  const bool fused = (off + xgw_bytes) <= ws_size;
  unsigned short* xg_w;
  unsigned short* ce_b;
  unsigned short* we_b;
  if (fused) {
    xg_w = (unsigned short*)alloc(xgw_bytes);
    ce_b = xg_w;          // consumed by g_c0 before g_w0 overwrites xg_w
    we_b = comb;          // consumed by g_w0 before lstm0 writes comb
  } else {
    xg_w = xg_c;
    ce_b = (unsigned short*)alloc((size_t)M * 128 * 2);
    we_b = (unsigned short*)alloc((size_t)M * 768 * 2);
  }
  unsigned short* h1 = xg_c;                        // free after level-1 lstm
  float* logits = (float*)(xg_c + (size_t)24 * 1024 * 1024);   // +48MB into xg_c

  // ---- prep ----
  cvt_bf16<<<1024, 256, 0, stream>>>((const float*)d_in[4],  wih_c0, 2048 * 128);
  cvt_bf16<<<1024, 256, 0, stream>>>((const float*)d_in[8],  wih_c1, 2048 * 512);
  cvt_bf16<<<1024, 256, 0, stream>>>((const float*)d_in[12], wih_w0, 2048 * 768);
  cvt_bf16<<<1024, 256, 0, stream>>>((const float*)d_in[16], wih_w1, 2048 * 512);
  cvt_bf16<<<1024, 256, 0, stream>>>((const float*)d_in[20], cls1b, 512 * 1024);
  cvt_bf16<<<64, 256, 0, stream>>>((const float*)d_in[22], cls2b, 15 * 512);
  cvt_bf16<<<4096, 256, 0, stream>>>(we, we_b, M * 768);
  whh_pack<<<256, 256, 0, stream>>>((const float*)d_in[5],  whh_c0);
  whh_pack<<<256, 256, 0, stream>>>((const float*)d_in[9],  whh_c1);
  whh_pack<<<256, 256, 0, stream>>>((const float*)d_in[13], whh_w0);
  whh_pack<<<256, 256, 0, stream>>>((const float*)d_in[17], whh_w1);
  bias_sum<<<8, 256, 0, stream>>>((const float*)d_in[6],  (const float*)d_in[7],  bs_c0, 2048);
  bias_sum<<<8, 256, 0, stream>>>((const float*)d_in[10], (const float*)d_in[11], bs_c1, 2048);
  bias_sum<<<8, 256, 0, stream>>>((const float*)d_in[14], (const float*)d_in[15], bs_w0, 2048);
  bias_sum<<<8, 256, 0, stream>>>((const float*)d_in[18], (const float*)d_in[19], bs_w1, 2048);
  embed_gather<<<8192, 256, 0, stream>>>(cid, etab, ce_b, M * 128);

  const int G2048 = (M >> 7) * (2048 >> 7);   // 4096
  const int G512  = (M >> 7) * (512 >> 7);    // 1024
  if (fused) {
    gemm_lds<0, 1><<<G2048, 256, 0, stream>>>(ce_b, 128, wih_c0, bs_c0, xg_c, M, 2048, 128);
    gemm_lds<0, 1><<<G2048, 256, 0, stream>>>(we_b, 768, wih_w0, bs_w0, xg_w, M, 2048, 768);
    lstm_mfma_ag<<<16, 1024, 0, stream>>>(whh_c0, xg_c, comb, 0,
                                          whh_w0, xg_w, comb, 512, T);   // A: AGPR variant
    gemm_lds<0, 1><<<G2048, 256, 0, stream>>>(comb, 1024, wih_c1, bs_c1, xg_c, M, 2048, 512);
    gemm_lds<0, 1><<<G2048, 256, 0, stream>>>(comb + 512, 1024, wih_w1, bs_w1, xg_w, M, 2048, 512);
    lstm_mfma<<<16, 1024, 0, stream>>>(whh_c1, xg_c, comb, 0,
                                       whh_w1, xg_w, comb, 512, T);      // B: R10 baseline
  } else {
    gemm_lds<0, 1><<<G2048, 256, 0, stream>>>(ce_b, 128, wih_c0, bs_c0, xg_c, M, 2048, 128);
    lstm_mfma<<<8, 1024, 0, stream>>>(whh_c0, xg_c, comb, 0, whh_c0, xg_c, comb, 0, T);
    gemm_lds<0, 1><<<G2048, 256, 0, stream>>>(comb, 1024, wih_c1, bs_c1, xg_c, M, 2048, 512);
    lstm_mfma<<<8, 1024, 0, stream>>>(whh_c1, xg_c, comb, 0, whh_c1, xg_c, comb, 0, T);
    gemm_lds<0, 1><<<G2048, 256, 0, stream>>>(we_b, 768, wih_w0, bs_w0, xg_c, M, 2048, 768);
    lstm_mfma<<<8, 1024, 0, stream>>>(whh_w0, xg_c, comb, 512, whh_w0, xg_c, comb, 512, T);
    gemm_lds<0, 1><<<G2048, 256, 0, stream>>>(comb + 512, 1024, wih_w1, bs_w1, xg_c, M, 2048, 512);
    lstm_mfma<<<8, 1024, 0, stream>>>(whh_w1, xg_c, comb, 512, whh_w1, xg_c, comb, 512, T);
  }
  // ---- classifier ----
  gemm_lds<1, 0><<<G512, 256, 0, stream>>>(comb, 1024, cls1b, (const float*)d_in[21], h1, M, 512, 1024);
  cls2_kernel<<<2048, 256, 0, stream>>>(h1, cls2b, (const float*)d_in[23], logits, M);
  // ---- CRF ----
  crf_num<<<64, 256, 0, stream>>>(logits, tags, (const float*)d_in[24], (const float*)d_in[25],
                                  (const float*)d_in[26], numb, T);
  crf_denom<<<64, 64, 0, stream>>>(logits, (const float*)d_in[24], (const float*)d_in[25],
                                   (const float*)d_in[26], denb, T);
  crf_final<<<1, 64, 0, stream>>>(numb, denb, (float*)d_out);
}

// Round 14
// 4116.467 us; speedup vs baseline: 1.7846x; 1.3638x over previous
//
#include <hip/hip_runtime.h>

#define DEVI __device__ __forceinline__

typedef __attribute__((ext_vector_type(8))) __bf16 bf16x8;
typedef __attribute__((ext_vector_type(4))) float f32x4;

// ---------- scalar helpers ----------
DEVI unsigned short f2b(float f) {           // f32 -> bf16 (RNE)
  unsigned u = __float_as_uint(f);
  u = u + 0x7fffu + ((u >> 16) & 1u);
  return (unsigned short)(u >> 16);
}
DEVI float lo16(unsigned u) { return __uint_as_float(u << 16); }
DEVI float hi16(unsigned u) { return __uint_as_float(u & 0xffff0000u); }
#if __has_builtin(__builtin_amdgcn_rcpf)
DEVI float rcpf(float x) { return __builtin_amdgcn_rcpf(x); }
#else
DEVI float rcpf(float x) { return 1.f / x; }
#endif
DEVI float sigm(float x) { return rcpf(1.f + __expf(-x)); }
DEVI float tanh_f(float x) { return fmaf(2.f, rcpf(1.f + __expf(-2.f * x)), -1.f); }

// ---------- fp8 e4m3fn encode ----------
#if __has_builtin(__builtin_amdgcn_cvt_pk_fp8_f32)
DEVI unsigned char f2e4m3(float f) {
  return (unsigned char)(__builtin_amdgcn_cvt_pk_fp8_f32(f, f, 0, false) & 0xff);
}
#else
DEVI unsigned char f2e4m3(float f) {   // software RNE e4m3fn
  unsigned u = __float_as_uint(f);
  unsigned s = (u >> 31) << 7;
  float a = fabsf(f);
  if (a >= 448.f) return (unsigned char)(s | 0x7e);
  if (a < 0.015625f) {                 // denorm, unit 2^-9
    int m = (int)rintf(a * 512.f);
    if (m >= 8) return (unsigned char)(s | 0x08);
    return (unsigned char)(s | m);
  }
  unsigned ur = u + 0x7FFFF + ((u >> 20) & 1);   // RNE at mantissa bit 20
  int e8 = (int)((ur >> 23) & 255) - 127 + 7;
  unsigned m3 = (ur >> 20) & 7;
  if (e8 > 15 || (e8 == 15 && m3 > 6)) return (unsigned char)(s | 0x7e);
  if (e8 <= 0) return (unsigned char)s;
  return (unsigned char)(s | (e8 << 3) | m3);
}
#endif

// ---------- prep kernels ----------
__global__ void cvt_bf16(const float* __restrict__ in, unsigned short* __restrict__ out, int n) {
  for (int i = blockIdx.x * blockDim.x + threadIdx.x; i < n; i += gridDim.x * blockDim.x)
    out[i] = f2b(in[i]);
}

// Whh (2,1024,256) f32 -> fp8 MFMA-A-fragment order:
// uint2 index = ((d*64 + mt)*8 + kf)*64 + lane; bytes j=0..7:
//   row = mt*16 + (lane&15); unit = row>>2; gate = row&3;
//   k = kf*32 + (lane>>4)*8 + j;  src = W[d][gate*256 + unit][k]
__global__ void whh_pack(const float* __restrict__ W, uint2* __restrict__ out) {
  int idx = blockIdx.x * blockDim.x + threadIdx.x;   // 65536 total
  if (idx >= 65536) return;
  int d = idx >> 15, rem = idx & 32767;
  int mt = rem >> 9, kf = (rem >> 6) & 7, lane = rem & 63;
  int row = mt * 16 + (lane & 15);
  int unit = row >> 2, gate = row & 3;
  int kb = kf * 32 + (lane >> 4) * 8;
  const float* w = W + (((size_t)d * 1024 + gate * 256 + unit) * 256 + kb);
  unsigned lo = 0, hi = 0;
  #pragma unroll
  for (int j = 0; j < 4; ++j) lo |= (unsigned)f2e4m3(w[j]) << (8 * j);
  #pragma unroll
  for (int j = 0; j < 4; ++j) hi |= (unsigned)f2e4m3(w[4 + j]) << (8 * j);
  out[idx] = make_uint2(lo, hi);
}

__global__ void bias_sum(const float* __restrict__ a, const float* __restrict__ b,
                         float* __restrict__ o, int n) {
  int i = blockIdx.x * blockDim.x + threadIdx.x;
  if (i < n) o[i] = a[i] + b[i];
}

__global__ void embed_gather(const int* __restrict__ ids, const float* __restrict__ tab,
                             unsigned short* __restrict__ out, int total) {
  for (int i = blockIdx.x * blockDim.x + threadIdx.x; i < total; i += gridDim.x * blockDim.x) {
    int bt = i >> 7, c = i & 127;
    out[i] = f2b(tab[(size_t)ids[bt] * 128 + c]);
  }
}

// ---------- GEMM (LDS-staged): C[M,N] = act(A[M,K](lda,bf16) @ W[N,K]^T + bias) -> bf16
// 128x128 tile, 256 thr (4 waves), K-step 32. (R11, measured good.)
template <int ACT, int PERM>
__global__ __launch_bounds__(256) void gemm_lds(const unsigned short* __restrict__ A, int lda,
                                                const unsigned short* __restrict__ W,
                                                const float* __restrict__ bias,
                                                unsigned short* __restrict__ C,
                                                int M, int N, int K) {
  const int ntiles = N >> 7;
  const int mt = blockIdx.x / ntiles;
  const int nt = blockIdx.x - mt * ntiles;
  const int m0 = mt << 7, n0 = nt << 7;
  const int tid = threadIdx.x;
  const int w = tid >> 6, lane = tid & 63, r = lane & 15, q = lane >> 4;
  __shared__ unsigned short lsA[4096], lsB[4096];
  f32x4 acc[16];
  #pragma unroll
  for (int i = 0; i < 16; ++i) acc[i] = f32x4{0.f, 0.f, 0.f, 0.f};

  const int srow = tid >> 2, sq = tid & 3;
  const int s0 = (srow << 2) | (sq ^ (srow & 3) ^ ((srow >> 2) & 3));
  const unsigned short* gA = A + (size_t)(m0 + srow) * lda + sq * 8;
  const unsigned short* gB = W + (size_t)(n0 + srow) * K + sq * 8;
  const size_t gAs = (size_t)64 * lda, gBs = (size_t)64 * K;
  const int sw = q ^ (r & 3) ^ ((r >> 2) & 3);

  for (int k0 = 0; k0 < K; k0 += 32) {
    uint4 va0 = *(const uint4*)(gA + k0);
    uint4 va1 = *(const uint4*)(gA + gAs + k0);
    uint4 vb0 = *(const uint4*)(gB + k0);
    uint4 vb1 = *(const uint4*)(gB + gBs + k0);
    *(uint4*)(lsA + s0 * 8) = va0;
    *(uint4*)(lsA + s0 * 8 + 2048) = va1;
    *(uint4*)(lsB + s0 * 8) = vb0;
    *(uint4*)(lsB + s0 * 8 + 2048) = vb1;
    __syncthreads();
    const bf16x8 a0 = *(const bf16x8*)(const void*)(lsA + ((w * 32 + r) * 4 + sw) * 8);
    const bf16x8 a1 = *(const bf16x8*)(const void*)(lsA + ((w * 32 + 16 + r) * 4 + sw) * 8);
    #pragma unroll
    for (int nf = 0; nf < 8; ++nf) {
      const bf16x8 b = *(const bf16x8*)(const void*)(lsB + ((nf * 16 + r) * 4 + sw) * 8);
      acc[nf]     = __builtin_amdgcn_mfma_f32_16x16x32_bf16(a0, b, acc[nf], 0, 0, 0);
      acc[8 + nf] = __builtin_amdgcn_mfma_f32_16x16x32_bf16(a1, b, acc[8 + nf], 0, 0, 0);
    }
    __syncthreads();
  }
  #pragma unroll
  for (int mf = 0; mf < 2; ++mf) {
    const int rbase = m0 + w * 32 + mf * 16 + q * 4;
    #pragma unroll
    for (int nf = 0; nf < 8; ++nf) {
      const f32x4 a = acc[mf * 8 + nf];
      const int col = n0 + nf * 16 + r;
      const float bv = bias[col];
      int oc = col;
      if constexpr (PERM) oc = (col & 1024) | ((col & 255) << 2) | ((col >> 8) & 3);
      #pragma unroll
      for (int i = 0; i < 4; ++i) {
        float v = a[i] + bv;
        if constexpr (ACT) v = fmaxf(v, 0.f);
        C[(size_t)(rbase + i) * N + oc] = f2b(v);
      }
    }
  }
}

// ---------- LSTM recurrence via MFMA fp8 ----------
// PF=1: keep kf=0,1 weight groups (8 uint2 = 16 VGPR) live across steps so the
// first 8 MFMAs after the barrier don't wait on the L2 stream. PF=0: exact R10.
template <int PF>
__global__ __launch_bounds__(1024, 4) void lstm_mfma_t(
    const uint2* __restrict__ W0, const unsigned short* __restrict__ x0,
    unsigned short* __restrict__ o0, int oo0,
    const uint2* __restrict__ W1, const unsigned short* __restrict__ x1,
    unsigned short* __restrict__ o1, int oo1, int T) {
  const int bid = blockIdx.x;
  const int sg = bid & 3, dir = (bid >> 2) & 1, grp = bid >> 3;
  const uint2* __restrict__ Wp = (grp ? W1 : W0) + (size_t)dir * 32768;
  const unsigned short* __restrict__ xg = grp ? x1 : x0;
  unsigned short* __restrict__ out = grp ? o1 : o0;
  const int outOff = grp ? oo1 : oo0;

  const int tid = threadIdx.x;
  const int w = tid >> 6, lane = tid & 63, q = lane >> 4, n = lane & 15;
  const int b = sg * 16 + n;

  __shared__ long hb[2][512];
  __shared__ unsigned short hout[2][16][264];
  hb[0][tid & 511] = 0;
  hb[1][tid & 511] = 0;

  float c[4] = {0.f, 0.f, 0.f, 0.f};
  const unsigned short* xb = xg + ((size_t)b * T) * 2048 + dir * 1024 + (w * 16 + q) * 4;
  const uint2* wbase = Wp + (size_t)(w * 32) * 64 + lane;
  unsigned short* orow = out + ((size_t)(sg * 16 + w) * T) * 1024 + outOff + dir * 256 + lane * 4;

  // PF: prefetch kf=0,1 weight groups (loop-invariant values, 16 VGPR)
  uint2 wpf[8];
  if constexpr (PF) {
    #pragma unroll
    for (int j = 0; j < 4; ++j) {
      wpf[j * 2]     = wbase[(size_t)(j * 8) * 64];
      wpf[j * 2 + 1] = wbase[(size_t)(j * 8 + 1) * 64];
    }
  }

  const int tstep = dir ? -1 : 1;
  int t = dir ? T - 1 : 0;
  uint2 xv[4];
  #pragma unroll
  for (int j = 0; j < 4; ++j)
    xv[j] = *(const uint2*)(xb + (size_t)t * 2048 + j * 16);
  __syncthreads();

  int cur = 0;
  for (int ti = 0; ti < T; ++ti) {
    if (ti) {
      const uint2 hv = *(const uint2*)&hout[cur][w][lane * 4];
      *(uint2*)(orow + (size_t)(t - tstep) * 1024) = hv;
    }
    uint2 xn[4];
    if (ti + 1 < T) {
      #pragma unroll
      for (int j = 0; j < 4; ++j)
        xn[j] = *(const uint2*)(xb + (size_t)(t + tstep) * 2048 + j * 16);
    }
    f32x4 acc[4];
    #pragma unroll
    for (int j = 0; j < 4; ++j) acc[j] = f32x4{0.f, 0.f, 0.f, 0.f};
    if constexpr (PF) {
      // kf=0,1 from the live registers (no L2 wait)
      #pragma unroll
      for (int kf = 0; kf < 2; ++kf) {
        const long bf = hb[cur][kf * 64 + q * 16 + n];
        #pragma unroll
        for (int j = 0; j < 4; ++j)
          acc[j] = __builtin_amdgcn_mfma_f32_16x16x32_fp8_fp8(
              __builtin_bit_cast(long, wpf[j * 2 + kf]), bf, acc[j], 0, 0, 0);
      }
      #pragma unroll
      for (int kf = 2; kf < 8; ++kf) {
        const long bf = hb[cur][kf * 64 + q * 16 + n];
        #pragma unroll
        for (int j = 0; j < 4; ++j) {
          const long a = __builtin_bit_cast(long, wbase[(size_t)(j * 8 + kf) * 64]);
          acc[j] = __builtin_amdgcn_mfma_f32_16x16x32_fp8_fp8(a, bf, acc[j], 0, 0, 0);
        }
      }
      // refresh the prefetch (same addresses; keeps values live for next iter)
      #pragma unroll
      for (int j = 0; j < 4; ++j) {
        wpf[j * 2]     = wbase[(size_t)(j * 8) * 64];
        wpf[j * 2 + 1] = wbase[(size_t)(j * 8 + 1) * 64];
      }
    } else {
      #pragma unroll
      for (int kf = 0; kf < 8; ++kf) {
        const long bf = hb[cur][kf * 64 + q * 16 + n];
        #pragma unroll
        for (int j = 0; j < 4; ++j) {
          const long a = __builtin_bit_cast(long, wbase[(size_t)(j * 8 + kf) * 64]);
          acc[j] = __builtin_amdgcn_mfma_f32_16x16x32_fp8_fp8(a, bf, acc[j], 0, 0, 0);
        }
      }
    }
    unsigned char* hw = (unsigned char*)&hb[cur ^ 1][0];
    #pragma unroll
    for (int j = 0; j < 4; ++j) {
      const int u = w * 16 + j * 4 + q;
      const float gi = acc[j][0] + lo16(xv[j].x);
      const float gf = acc[j][1] + hi16(xv[j].x);
      const float gg = acc[j][2] + lo16(xv[j].y);
      const float go = acc[j][3] + hi16(xv[j].y);
      c[j] = sigm(gf) * c[j] + sigm(gi) * tanh_f(gg);
      const float h = sigm(go) * tanh_f(c[j]);
      hw[(u >> 3) * 128 + n * 8 + (u & 7)] = f2e4m3(h);
      hout[cur ^ 1][n][u] = f2b(h);
    }
    __syncthreads();
    #pragma unroll
    for (int j = 0; j < 4; ++j) xv[j] = xn[j];
    t += tstep;
    cur ^= 1;
  }
  const uint2 hv = *(const uint2*)&hout[cur][w][lane * 4];
  *(uint2*)(orow + (size_t)(t - tstep) * 1024) = hv;
}

// ---------- classifier layer 2 ----------
__global__ __launch_bounds__(256) void cls2_kernel(const unsigned short* __restrict__ h1,
                                                   const unsigned short* __restrict__ w2,
                                                   const float* __restrict__ b2,
                                                   float* __restrict__ logits, int M) {
  int idx = blockIdx.x * 256 + threadIdx.x;
  int row = idx >> 4, n = idx & 15;
  if (row >= M || n >= 15) return;
  const unsigned* hp = (const unsigned*)(h1 + (size_t)row * 512);
  const unsigned* wp = (const unsigned*)(w2 + (size_t)n * 512);
  float acc = 0.f;
  #pragma unroll 8
  for (int k = 0; k < 256; ++k) {
    unsigned uh = hp[k], uw = wp[k];
    acc = fmaf(lo16(uh), lo16(uw), acc);
    acc = fmaf(hi16(uh), hi16(uw), acc);
  }
  logits[(size_t)row * 16 + n] = acc + b2[n];
}

// ---------- CRF ----------
__global__ __launch_bounds__(256) void crf_num(const float* __restrict__ logits,
                                               const int* __restrict__ tags,
                                               const float* __restrict__ start,
                                               const float* __restrict__ end,
                                               const float* __restrict__ trans,
                                               float* __restrict__ numout, int T) {
  int b = blockIdx.x, tid = threadIdx.x;
  const int* tg = tags + (size_t)b * T;
  float s = 0.f;
  for (int t = tid; t < T; t += 256) {
    int cur = tg[t];
    s += logits[((size_t)b * T + t) * 16 + cur];
    if (t > 0) s += trans[tg[t - 1] * 15 + cur];
  }
  #pragma unroll
  for (int off = 32; off > 0; off >>= 1) s += __shfl_down(s, off, 64);
  __shared__ float red[4];
  if ((tid & 63) == 0) red[tid >> 6] = s;
  __syncthreads();
  if (tid == 0)
    numout[b] = red[0] + red[1] + red[2] + red[3] + start[tg[0]] + end[tg[T - 1]];
}

__global__ void crf_denom(const float* __restrict__ logits, const float* __restrict__ start,
                          const float* __restrict__ end, const float* __restrict__ trans,
                          float* __restrict__ denout, int T) {
  int b = blockIdx.x;
  int lane = threadIdx.x;
  int kp = lane < 15 ? lane : 0;
  float tcol[15];
  #pragma unroll
  for (int k = 0; k < 15; ++k) tcol[k] = trans[k * 15 + kp];
  float score = start[kp] + logits[((size_t)b * T) * 16 + kp];
  for (int t = 1; t < T; ++t) {
    float e = logits[((size_t)b * T + t) * 16 + kp];
    float s[15], m = -3.4e38f;
    #pragma unroll
    for (int k = 0; k < 15; ++k) {
      s[k] = __shfl(score, k, 64) + tcol[k];
      m = fmaxf(m, s[k]);
    }
    float sum = 0.f;
    #pragma unroll
    for (int k = 0; k < 15; ++k) sum += __expf(s[k] - m);
    score = e + m + __logf(sum);
  }
  float x = score + end[kp];
  float m = -3.4e38f;
  #pragma unroll
  for (int k = 0; k < 15; ++k) m = fmaxf(m, __shfl(x, k, 64));
  float sum = 0.f;
  #pragma unroll
  for (int k = 0; k < 15; ++k) sum += __expf(__shfl(x, k, 64) - m);
  if (lane == 0) denout[b] = m + __logf(sum);
}

__global__ void crf_final(const float* __restrict__ num, const float* __restrict__ den,
                          float* __restrict__ out) {
  int l = threadIdx.x;
  float v = den[l] - num[l];
  #pragma unroll
  for (int off = 32; off > 0; off >>= 1) v += __shfl_xor(v, off, 64);
  if (l == 0) out[0] = v * (1.f / 64.f);
}

// ---------- host ----------
extern "C" void kernel_launch(void* const* d_in, const int* in_sizes, int n_in,
                              void* d_out, int out_size, void* d_ws, size_t ws_size,
                              hipStream_t stream) {
  const int B = 64, T = 512, M = B * T;   // 32768
  const float* we   = (const float*)d_in[1];
  const int*   cid  = (const int*)d_in[0];
  const int*   tags = (const int*)d_in[2];
  const float* etab = (const float*)d_in[3];

  char* ws = (char*)d_ws;
  size_t off = 0;
  auto alloc = [&](size_t bytes) -> char* {
    char* p = ws + off;
    off += (bytes + 255) & ~(size_t)255;
    return p;
  };
  // small, permanent
  unsigned short* wih_c0 = (unsigned short*)alloc((size_t)2048 * 128 * 2);
  unsigned short* wih_c1 = (unsigned short*)alloc((size_t)2048 * 512 * 2);
  unsigned short* wih_w0 = (unsigned short*)alloc((size_t)2048 * 768 * 2);
  unsigned short* wih_w1 = (unsigned short*)alloc((size_t)2048 * 512 * 2);
  unsigned short* cls1b  = (unsigned short*)alloc((size_t)512 * 1024 * 2);
  unsigned short* cls2b  = (unsigned short*)alloc((size_t)15 * 512 * 2);
  uint2* whh_c0 = (uint2*)alloc((size_t)65536 * 8);
  uint2* whh_c1 = (uint2*)alloc((size_t)65536 * 8);
  uint2* whh_w0 = (uint2*)alloc((size_t)65536 * 8);
  uint2* whh_w1 = (uint2*)alloc((size_t)65536 * 8);
  float* bs_c0 = (float*)alloc(2048 * 4);
  float* bs_c1 = (float*)alloc(2048 * 4);
  float* bs_w0 = (float*)alloc(2048 * 4);
  float* bs_w1 = (float*)alloc(2048 * 4);
  float* numb = (float*)alloc(64 * 4);
  float* denb = (float*)alloc(64 * 4);
  // big
  unsigned short* comb = (unsigned short*)alloc((size_t)M * 1024 * 2);   // 64 MB
  unsigned short* xg_c = (unsigned short*)alloc((size_t)M * 2048 * 2);   // 128 MB
  const size_t xgw_bytes = (size_t)M * 2048 * 2;
  const bool fused = (off + xgw_bytes) <= ws_size;
  unsigned short* xg_w;
  unsigned short* ce_b;
  unsigned short* we_b;
  if (fused) {
    xg_w = (unsigned short*)alloc(xgw_bytes);
    ce_b = xg_w;          // consumed by g_c0 before g_w0 overwrites xg_w
    we_b = comb;          // consumed by g_w0 before lstm0 writes comb
  } else {
    xg_w = xg_c;
    ce_b = (unsigned short*)alloc((size_t)M * 128 * 2);
    we_b = (unsigned short*)alloc((size_t)M * 768 * 2);
  }
  unsigned short* h1 = xg_c;                        // free after level-1 lstm
  float* logits = (float*)(xg_c + (size_t)24 * 1024 * 1024);   // +48MB into xg_c

  // ---- prep ----
  cvt_bf16<<<1024, 256, 0, stream>>>((const float*)d_in[4],  wih_c0, 2048 * 128);
  cvt_bf16<<<1024, 256, 0, stream>>>((const float*)d_in[8],  wih_c1, 2048 * 512);
  cvt_bf16<<<1024, 256, 0, stream>>>((const float*)d_in[12], wih_w0, 2048 * 768);
  cvt_bf16<<<1024, 256, 0, stream>>>((const float*)d_in[16], wih_w1, 2048 * 512);
  cvt_bf16<<<1024, 256, 0, stream>>>((const float*)d_in[20], cls1b, 512 * 1024);
  cvt_bf16<<<64, 256, 0, stream>>>((const float*)d_in[22], cls2b, 15 * 512);
  cvt_bf16<<<4096, 256, 0, stream>>>(we, we_b, M * 768);
  whh_pack<<<256, 256, 0, stream>>>((const float*)d_in[5],  whh_c0);
  whh_pack<<<256, 256, 0, stream>>>((const float*)d_in[9],  whh_c1);
  whh_pack<<<256, 256, 0, stream>>>((const float*)d_in[13], whh_w0);
  whh_pack<<<256, 256, 0, stream>>>((const float*)d_in[17], whh_w1);
  bias_sum<<<8, 256, 0, stream>>>((const float*)d_in[6],  (const float*)d_in[7],  bs_c0, 2048);
  bias_sum<<<8, 256, 0, stream>>>((const float*)d_in[10], (const float*)d_in[11], bs_c1, 2048);
  bias_sum<<<8, 256, 0, stream>>>((const float*)d_in[14], (const float*)d_in[15], bs_w0, 2048);
  bias_sum<<<8, 256, 0, stream>>>((const float*)d_in[18], (const float*)d_in[19], bs_w1, 2048);
  embed_gather<<<8192, 256, 0, stream>>>(cid, etab, ce_b, M * 128);

  const int G2048 = (M >> 7) * (2048 >> 7);   // 4096
  const int G512  = (M >> 7) * (512 >> 7);    // 1024
  if (fused) {
    gemm_lds<0, 1><<<G2048, 256, 0, stream>>>(ce_b, 128, wih_c0, bs_c0, xg_c, M, 2048, 128);
    gemm_lds<0, 1><<<G2048, 256, 0, stream>>>(we_b, 768, wih_w0, bs_w0, xg_w, M, 2048, 768);
    lstm_mfma_t<1><<<16, 1024, 0, stream>>>(whh_c0, xg_c, comb, 0,
                                            whh_w0, xg_w, comb, 512, T);   // A: prefetch
    gemm_lds<0, 1><<<G2048, 256, 0, stream>>>(comb, 1024, wih_c1, bs_c1, xg_c, M, 2048, 512);
    gemm_lds<0, 1><<<G2048, 256, 0, stream>>>(comb + 512, 1024, wih_w1, bs_w1, xg_w, M, 2048, 512);
    lstm_mfma_t<0><<<16, 1024, 0, stream>>>(whh_c1, xg_c, comb, 0,
                                            whh_w1, xg_w, comb, 512, T);   // B: R10 exact
  } else {
    gemm_lds<0, 1><<<G2048, 256, 0, stream>>>(ce_b, 128, wih_c0, bs_c0, xg_c, M, 2048, 128);
    lstm_mfma_t<0><<<8, 1024, 0, stream>>>(whh_c0, xg_c, comb, 0, whh_c0, xg_c, comb, 0, T);
    gemm_lds<0, 1><<<G2048, 256, 0, stream>>>(comb, 1024, wih_c1, bs_c1, xg_c, M, 2048, 512);
    lstm_mfma_t<0><<<8, 1024, 0, stream>>>(whh_c1, xg_c, comb, 0, whh_c1, xg_c, comb, 0, T);
    gemm_lds<0, 1><<<G2048, 256, 0, stream>>>(we_b, 768, wih_w0, bs_w0, xg_c, M, 2048, 768);
    lstm_mfma_t<0><<<8, 1024, 0, stream>>>(whh_w0, xg_c, comb, 512, whh_w0, xg_c, comb, 512, T);
    gemm_lds<0, 1><<<G2048, 256, 0, stream>>>(comb + 512, 1024, wih_w1, bs_w1, xg_c, M, 2048, 512);
    lstm_mfma_t<0><<<8, 1024, 0, stream>>>(whh_w1, xg_c, comb, 512, whh_w1, xg_c, comb, 512, T);
  }
  // ---- classifier ----
  gemm_lds<1, 0><<<G512, 256, 0, stream>>>(comb, 1024, cls1b, (const float*)d_in[21], h1, M, 512, 1024);
  cls2_kernel<<<2048, 256, 0, stream>>>(h1, cls2b, (const float*)d_in[23], logits, M);
  // ---- CRF ----
  crf_num<<<64, 256, 0, stream>>>(logits, tags, (const float*)d_in[24], (const float*)d_in[25],
                                  (const float*)d_in[26], numb, T);
  crf_denom<<<64, 64, 0, stream>>>(logits, (const float*)d_in[24], (const float*)d_in[25],
                                   (const float*)d_in[26], denb, T);
  crf_final<<<1, 64, 0, stream>>>(numb, denb, (float*)d_out);
}

// Round 15
// 3518.022 us; speedup vs baseline: 2.0881x; 1.1701x over previous
//
#include <hip/hip_runtime.h>

#define DEVI __device__ __forceinline__

typedef __attribute__((ext_vector_type(8))) __bf16 bf16x8;
typedef __attribute__((ext_vector_type(4))) float f32x4;

// ---------- scalar helpers ----------
DEVI unsigned short f2b(float f) {           // f32 -> bf16 (RNE)
  unsigned u = __float_as_uint(f);
  u = u + 0x7fffu + ((u >> 16) & 1u);
  return (unsigned short)(u >> 16);
}
DEVI float lo16(unsigned u) { return __uint_as_float(u << 16); }
DEVI float hi16(unsigned u) { return __uint_as_float(u & 0xffff0000u); }
#if __has_builtin(__builtin_amdgcn_rcpf)
DEVI float rcpf(float x) { return __builtin_amdgcn_rcpf(x); }
#else
DEVI float rcpf(float x) { return 1.f / x; }
#endif
DEVI float sigm(float x) { return rcpf(1.f + __expf(-x)); }
DEVI float tanh_f(float x) { return fmaf(2.f, rcpf(1.f + __expf(-2.f * x)), -1.f); }

// ---------- fp8 e4m3fn encode ----------
#if __has_builtin(__builtin_amdgcn_cvt_pk_fp8_f32)
DEVI unsigned char f2e4m3(float f) {
  return (unsigned char)(__builtin_amdgcn_cvt_pk_fp8_f32(f, f, 0, false) & 0xff);
}
#else
DEVI unsigned char f2e4m3(float f) {   // software RNE e4m3fn
  unsigned u = __float_as_uint(f);
  unsigned s = (u >> 31) << 7;
  float a = fabsf(f);
  if (a >= 448.f) return (unsigned char)(s | 0x7e);
  if (a < 0.015625f) {                 // denorm, unit 2^-9
    int m = (int)rintf(a * 512.f);
    if (m >= 8) return (unsigned char)(s | 0x08);
    return (unsigned char)(s | m);
  }
  unsigned ur = u + 0x7FFFF + ((u >> 20) & 1);   // RNE at mantissa bit 20
  int e8 = (int)((ur >> 23) & 255) - 127 + 7;
  unsigned m3 = (ur >> 20) & 7;
  if (e8 > 15 || (e8 == 15 && m3 > 6)) return (unsigned char)(s | 0x7e);
  if (e8 <= 0) return (unsigned char)s;
  return (unsigned char)(s | (e8 << 3) | m3);
}
#endif

// ---------- prep kernels ----------
__global__ void cvt_bf16(const float* __restrict__ in, unsigned short* __restrict__ out, int n) {
  for (int i = blockIdx.x * blockDim.x + threadIdx.x; i < n; i += gridDim.x * blockDim.x)
    out[i] = f2b(in[i]);
}

// Whh (2,1024,256) f32 -> fp8 MFMA-A-fragment order:
// uint2 index = ((d*64 + mt)*8 + kf)*64 + lane; bytes j=0..7:
//   row = mt*16 + (lane&15); unit = row>>2; gate = row&3;
//   k = kf*32 + (lane>>4)*8 + j;  src = W[d][gate*256 + unit][k]
__global__ void whh_pack(const float* __restrict__ W, uint2* __restrict__ out) {
  int idx = blockIdx.x * blockDim.x + threadIdx.x;   // 65536 total
  if (idx >= 65536) return;
  int d = idx >> 15, rem = idx & 32767;
  int mt = rem >> 9, kf = (rem >> 6) & 7, lane = rem & 63;
  int row = mt * 16 + (lane & 15);
  int unit = row >> 2, gate = row & 3;
  int kb = kf * 32 + (lane >> 4) * 8;
  const float* w = W + (((size_t)d * 1024 + gate * 256 + unit) * 256 + kb);
  unsigned lo = 0, hi = 0;
  #pragma unroll
  for (int j = 0; j < 4; ++j) lo |= (unsigned)f2e4m3(w[j]) << (8 * j);
  #pragma unroll
  for (int j = 0; j < 4; ++j) hi |= (unsigned)f2e4m3(w[4 + j]) << (8 * j);
  out[idx] = make_uint2(lo, hi);
}

__global__ void bias_sum(const float* __restrict__ a, const float* __restrict__ b,
                         float* __restrict__ o, int n) {
  int i = blockIdx.x * blockDim.x + threadIdx.x;
  if (i < n) o[i] = a[i] + b[i];
}

__global__ void embed_gather(const int* __restrict__ ids, const float* __restrict__ tab,
                             unsigned short* __restrict__ out, int total) {
  for (int i = blockIdx.x * blockDim.x + threadIdx.x; i < total; i += gridDim.x * blockDim.x) {
    int bt = i >> 7, c = i & 127;
    out[i] = f2b(tab[(size_t)ids[bt] * 128 + c]);
  }
}

// ---------- GEMM (LDS-staged): C[M,N] = act(A[M,K](lda,bf16) @ W[N,K]^T + bias) -> bf16
// 128x128 tile, 256 thr (4 waves), K-step 32. (R11, measured good.)
template <int ACT, int PERM>
__global__ __launch_bounds__(256) void gemm_lds(const unsigned short* __restrict__ A, int lda,
                                                const unsigned short* __restrict__ W,
                                                const float* __restrict__ bias,
                                                unsigned short* __restrict__ C,
                                                int M, int N, int K) {
  const int ntiles = N >> 7;
  const int mt = blockIdx.x / ntiles;
  const int nt = blockIdx.x - mt * ntiles;
  const int m0 = mt << 7, n0 = nt << 7;
  const int tid = threadIdx.x;
  const int w = tid >> 6, lane = tid & 63, r = lane & 15, q = lane >> 4;
  __shared__ unsigned short lsA[4096], lsB[4096];
  f32x4 acc[16];
  #pragma unroll
  for (int i = 0; i < 16; ++i) acc[i] = f32x4{0.f, 0.f, 0.f, 0.f};

  const int srow = tid >> 2, sq = tid & 3;
  const int s0 = (srow << 2) | (sq ^ (srow & 3) ^ ((srow >> 2) & 3));
  const unsigned short* gA = A + (size_t)(m0 + srow) * lda + sq * 8;
  const unsigned short* gB = W + (size_t)(n0 + srow) * K + sq * 8;
  const size_t gAs = (size_t)64 * lda, gBs = (size_t)64 * K;
  const int sw = q ^ (r & 3) ^ ((r >> 2) & 3);

  for (int k0 = 0; k0 < K; k0 += 32) {
    uint4 va0 = *(const uint4*)(gA + k0);
    uint4 va1 = *(const uint4*)(gA + gAs + k0);
    uint4 vb0 = *(const uint4*)(gB + k0);
    uint4 vb1 = *(const uint4*)(gB + gBs + k0);
    *(uint4*)(lsA + s0 * 8) = va0;
    *(uint4*)(lsA + s0 * 8 + 2048) = va1;
    *(uint4*)(lsB + s0 * 8) = vb0;
    *(uint4*)(lsB + s0 * 8 + 2048) = vb1;
    __syncthreads();
    const bf16x8 a0 = *(const bf16x8*)(const void*)(lsA + ((w * 32 + r) * 4 + sw) * 8);
    const bf16x8 a1 = *(const bf16x8*)(const void*)(lsA + ((w * 32 + 16 + r) * 4 + sw) * 8);
    #pragma unroll
    for (int nf = 0; nf < 8; ++nf) {
      const bf16x8 b = *(const bf16x8*)(const void*)(lsB + ((nf * 16 + r) * 4 + sw) * 8);
      acc[nf]     = __builtin_amdgcn_mfma_f32_16x16x32_bf16(a0, b, acc[nf], 0, 0, 0);
      acc[8 + nf] = __builtin_amdgcn_mfma_f32_16x16x32_bf16(a1, b, acc[8 + nf], 0, 0, 0);
    }
    __syncthreads();
  }
  #pragma unroll
  for (int mf = 0; mf < 2; ++mf) {
    const int rbase = m0 + w * 32 + mf * 16 + q * 4;
    #pragma unroll
    for (int nf = 0; nf < 8; ++nf) {
      const f32x4 a = acc[mf * 8 + nf];
      const int col = n0 + nf * 16 + r;
      const float bv = bias[col];
      int oc = col;
      if constexpr (PERM) oc = (col & 1024) | ((col & 255) << 2) | ((col >> 8) & 3);
      #pragma unroll
      for (int i = 0; i < 4; ++i) {
        float v = a[i] + bv;
        if constexpr (ACT) v = fmaxf(v, 0.f);
        C[(size_t)(rbase + i) * N + oc] = f2b(v);
      }
    }
  }
}

// ---------- LSTM recurrence via MFMA fp8, 16 samples per block (EXACT R9 form) ----------
// Block = (pathway, dir, sample-group of 16). 1024 threads = 16 waves, 1 block/CU.
// wreg[32] preload: compiler remats it into the loop BUT emits the 32 weight loads
// as one early batch per iteration (max bytes in flight) -- measured 1213us vs 1487
// for in-loop indexed loads (R9 vs R13/R14). Do not remove.
__global__ __launch_bounds__(1024, 4) void lstm_mfma(
    const uint2* __restrict__ W0, const unsigned short* __restrict__ x0,
    unsigned short* __restrict__ o0, int oo0,
    const uint2* __restrict__ W1, const unsigned short* __restrict__ x1,
    unsigned short* __restrict__ o1, int oo1, int T) {
  const int bid = blockIdx.x;
  const int sg = bid & 3, dir = (bid >> 2) & 1, grp = bid >> 3;
  const uint2* __restrict__ Wp = (grp ? W1 : W0) + (size_t)dir * 32768;
  const unsigned short* __restrict__ xg = grp ? x1 : x0;
  unsigned short* __restrict__ out = grp ? o1 : o0;
  const int outOff = grp ? oo1 : oo0;

  const int tid = threadIdx.x;
  const int w = tid >> 6, lane = tid & 63, q = lane >> 4, n = lane & 15;
  const int b = sg * 16 + n;

  __shared__ long hb[2][512];                 // fp8 h B-fragments (MFMA input)
  __shared__ unsigned short hout[2][16][264]; // bf16 h rows, padded (store staging)
  hb[0][tid & 511] = 0;
  hb[1][tid & 511] = 0;

  // ---- preload this wave's Whh slice (see note above: scheduling effect) ----
  long wreg[32];
  {
    const uint2* ap = Wp + (size_t)(w * 32) * 64 + lane;
    #pragma unroll
    for (int i = 0; i < 32; ++i)
      wreg[i] = __builtin_bit_cast(long, ap[(size_t)i * 64]);
  }

  float c[4] = {0.f, 0.f, 0.f, 0.f};
  const unsigned short* xb = xg + ((size_t)b * T) * 2048 + dir * 1024 + (w * 16 + q) * 4;
  // wave w cooperatively stores sample (sg*16+w)'s output row
  unsigned short* orow = out + ((size_t)(sg * 16 + w) * T) * 1024 + outOff + dir * 256 + lane * 4;

  const int tstep = dir ? -1 : 1;
  int t = dir ? T - 1 : 0;
  // prefetch first step's xg
  uint2 xv[4];
  #pragma unroll
  for (int j = 0; j < 4; ++j)
    xv[j] = *(const uint2*)(xb + (size_t)t * 2048 + j * 16);
  __syncthreads();

  int cur = 0;
  for (int ti = 0; ti < T; ++ti) {
    // coalesced store of previous step's h (written into hout[cur] last iter)
    if (ti) {
      const uint2 hv = *(const uint2*)&hout[cur][w][lane * 4];
      *(uint2*)(orow + (size_t)(t - tstep) * 1024) = hv;
    }
    // prefetch next step's xg (consumed after next barrier)
    uint2 xn[4];
    if (ti + 1 < T) {
      #pragma unroll
      for (int j = 0; j < 4; ++j)
        xn[j] = *(const uint2*)(xb + (size_t)(t + tstep) * 2048 + j * 16);
    }
    // MFMA: acc[j] = Whh-tile(w*4+j) x h
    f32x4 acc[4];
    #pragma unroll
    for (int j = 0; j < 4; ++j) acc[j] = f32x4{0.f, 0.f, 0.f, 0.f};
    #pragma unroll
    for (int kf = 0; kf < 8; ++kf) {
      const long bf = hb[cur][kf * 64 + q * 16 + n];
      #pragma unroll
      for (int j = 0; j < 4; ++j)
        acc[j] = __builtin_amdgcn_mfma_f32_16x16x32_fp8_fp8(wreg[j * 8 + kf], bf, acc[j], 0, 0, 0);
    }
    // cell update: lane owns (unit u, sample n) fully
    unsigned char* hw = (unsigned char*)&hb[cur ^ 1][0];
    #pragma unroll
    for (int j = 0; j < 4; ++j) {
      const int u = w * 16 + j * 4 + q;
      const float gi = acc[j][0] + lo16(xv[j].x);
      const float gf = acc[j][1] + hi16(xv[j].x);
      const float gg = acc[j][2] + lo16(xv[j].y);
      const float go = acc[j][3] + hi16(xv[j].y);
      c[j] = sigm(gf) * c[j] + sigm(gi) * tanh_f(gg);
      const float h = sigm(go) * tanh_f(c[j]);
      hw[(u >> 3) * 128 + n * 8 + (u & 7)] = f2e4m3(h);
      hout[cur ^ 1][n][u] = f2b(h);
    }
    __syncthreads();                   // new h visible; old buffers free
    #pragma unroll
    for (int j = 0; j < 4; ++j) xv[j] = xn[j];
    t += tstep;
    cur ^= 1;
  }
  // epilogue: store last step's h
  const uint2 hv = *(const uint2*)&hout[cur][w][lane * 4];
  *(uint2*)(orow + (size_t)(t - tstep) * 1024) = hv;
}

// ---------- classifier layer 2 ----------
__global__ __launch_bounds__(256) void cls2_kernel(const unsigned short* __restrict__ h1,
                                                   const unsigned short* __restrict__ w2,
                                                   const float* __restrict__ b2,
                                                   float* __restrict__ logits, int M) {
  int idx = blockIdx.x * 256 + threadIdx.x;
  int row = idx >> 4, n = idx & 15;
  if (row >= M || n >= 15) return;
  const unsigned* hp = (const unsigned*)(h1 + (size_t)row * 512);
  const unsigned* wp = (const unsigned*)(w2 + (size_t)n * 512);
  float acc = 0.f;
  #pragma unroll 8
  for (int k = 0; k < 256; ++k) {
    unsigned uh = hp[k], uw = wp[k];
    acc = fmaf(lo16(uh), lo16(uw), acc);
    acc = fmaf(hi16(uh), hi16(uw), acc);
  }
  logits[(size_t)row * 16 + n] = acc + b2[n];
}

// ---------- CRF ----------
__global__ __launch_bounds__(256) void crf_num(const float* __restrict__ logits,
                                               const int* __restrict__ tags,
                                               const float* __restrict__ start,
                                               const float* __restrict__ end,
                                               const float* __restrict__ trans,
                                               float* __restrict__ numout, int T) {
  int b = blockIdx.x, tid = threadIdx.x;
  const int* tg = tags + (size_t)b * T;
  float s = 0.f;
  for (int t = tid; t < T; t += 256) {
    int cur = tg[t];
    s += logits[((size_t)b * T + t) * 16 + cur];
    if (t > 0) s += trans[tg[t - 1] * 15 + cur];
  }
  #pragma unroll
  for (int off = 32; off > 0; off >>= 1) s += __shfl_down(s, off, 64);
  __shared__ float red[4];
  if ((tid & 63) == 0) red[tid >> 6] = s;
  __syncthreads();
  if (tid == 0)
    numout[b] = red[0] + red[1] + red[2] + red[3] + start[tg[0]] + end[tg[T - 1]];
}

__global__ void crf_denom(const float* __restrict__ logits, const float* __restrict__ start,
                          const float* __restrict__ end, const float* __restrict__ trans,
                          float* __restrict__ denout, int T) {
  int b = blockIdx.x;
  int lane = threadIdx.x;
  int kp = lane < 15 ? lane : 0;
  float tcol[15];
  #pragma unroll
  for (int k = 0; k < 15; ++k) tcol[k] = trans[k * 15 + kp];
  float score = start[kp] + logits[((size_t)b * T) * 16 + kp];
  for (int t = 1; t < T; ++t) {
    float e = logits[((size_t)b * T + t) * 16 + kp];
    float s[15], m = -3.4e38f;
    #pragma unroll
    for (int k = 0; k < 15; ++k) {
      s[k] = __shfl(score, k, 64) + tcol[k];
      m = fmaxf(m, s[k]);
    }
    float sum = 0.f;
    #pragma unroll
    for (int k = 0; k < 15; ++k) sum += __expf(s[k] - m);
    score = e + m + __logf(sum);
  }
  float x = score + end[kp];
  float m = -3.4e38f;
  #pragma unroll
  for (int k = 0; k < 15; ++k) m = fmaxf(m, __shfl(x, k, 64));
  float sum = 0.f;
  #pragma unroll
  for (int k = 0; k < 15; ++k) sum += __expf(__shfl(x, k, 64) - m);
  if (lane == 0) denout[b] = m + __logf(sum);
}

__global__ void crf_final(const float* __restrict__ num, const float* __restrict__ den,
                          float* __restrict__ out) {
  int l = threadIdx.x;
  float v = den[l] - num[l];
  #pragma unroll
  for (int off = 32; off > 0; off >>= 1) v += __shfl_xor(v, off, 64);
  if (l == 0) out[0] = v * (1.f / 64.f);
}

// ---------- host ----------
extern "C" void kernel_launch(void* const* d_in, const int* in_sizes, int n_in,
                              void* d_out, int out_size, void* d_ws, size_t ws_size,
                              hipStream_t stream) {
  const int B = 64, T = 512, M = B * T;   // 32768
  const float* we   = (const float*)d_in[1];
  const int*   cid  = (const int*)d_in[0];
  const int*   tags = (const int*)d_in[2];
  const float* etab = (const float*)d_in[3];

  char* ws = (char*)d_ws;
  size_t off = 0;
  auto alloc = [&](size_t bytes) -> char* {
    char* p = ws + off;
    off += (bytes + 255) & ~(size_t)255;
    return p;
  };
  // small, permanent
  unsigned short* wih_c0 = (unsigned short*)alloc((size_t)2048 * 128 * 2);
  unsigned short* wih_c1 = (unsigned short*)alloc((size_t)2048 * 512 * 2);
  unsigned short* wih_w0 = (unsigned short*)alloc((size_t)2048 * 768 * 2);
  unsigned short* wih_w1 = (unsigned short*)alloc((size_t)2048 * 512 * 2);
  unsigned short* cls1b  = (unsigned short*)alloc((size_t)512 * 1024 * 2);
  unsigned short* cls2b  = (unsigned short*)alloc((size_t)15 * 512 * 2);
  uint2* whh_c0 = (uint2*)alloc((size_t)65536 * 8);
  uint2* whh_c1 = (uint2*)alloc((size_t)65536 * 8);
  uint2* whh_w0 = (uint2*)alloc((size_t)65536 * 8);
  uint2* whh_w1 = (uint2*)alloc((size_t)65536 * 8);
  float* bs_c0 = (float*)alloc(2048 * 4);
  float* bs_c1 = (float*)alloc(2048 * 4);
  float* bs_w0 = (float*)alloc(2048 * 4);
  float* bs_w1 = (float*)alloc(2048 * 4);
  float* numb = (float*)alloc(64 * 4);
  float* denb = (float*)alloc(64 * 4);
  // big
  unsigned short* comb = (unsigned short*)alloc((size_t)M * 1024 * 2);   // 64 MB
  unsigned short* xg_c = (unsigned short*)alloc((size_t)M * 2048 * 2);   // 128 MB
  const size_t xgw_bytes = (size_t)M * 2048 * 2;
  const bool fused = (off + xgw_bytes) <= ws_size;
  unsigned short* xg_w;
  unsigned short* ce_b;
  unsigned short* we_b;
  if (fused) {
    xg_w = (unsigned short*)alloc(xgw_bytes);
    ce_b = xg_w;          // consumed by g_c0 before g_w0 overwrites xg_w
    we_b = comb;          // consumed by g_w0 before lstm0 writes comb
  } else {
    xg_w = xg_c;
    ce_b = (unsigned short*)alloc((size_t)M * 128 * 2);
    we_b = (unsigned short*)alloc((size_t)M * 768 * 2);
  }
  unsigned short* h1 = xg_c;                        // free after level-1 lstm
  float* logits = (float*)(xg_c + (size_t)24 * 1024 * 1024);   // +48MB into xg_c

  // ---- prep ----
  cvt_bf16<<<1024, 256, 0, stream>>>((const float*)d_in[4],  wih_c0, 2048 * 128);
  cvt_bf16<<<1024, 256, 0, stream>>>((const float*)d_in[8],  wih_c1, 2048 * 512);
  cvt_bf16<<<1024, 256, 0, stream>>>((const float*)d_in[12], wih_w0, 2048 * 768);
  cvt_bf16<<<1024, 256, 0, stream>>>((const float*)d_in[16], wih_w1, 2048 * 512);
  cvt_bf16<<<1024, 256, 0, stream>>>((const float*)d_in[20], cls1b, 512 * 1024);
  cvt_bf16<<<64, 256, 0, stream>>>((const float*)d_in[22], cls2b, 15 * 512);
  cvt_bf16<<<4096, 256, 0, stream>>>(we, we_b, M * 768);
  whh_pack<<<256, 256, 0, stream>>>((const float*)d_in[5],  whh_c0);
  whh_pack<<<256, 256, 0, stream>>>((const float*)d_in[9],  whh_c1);
  whh_pack<<<256, 256, 0, stream>>>((const float*)d_in[13], whh_w0);
  whh_pack<<<256, 256, 0, stream>>>((const float*)d_in[17], whh_w1);
  bias_sum<<<8, 256, 0, stream>>>((const float*)d_in[6],  (const float*)d_in[7],  bs_c0, 2048);
  bias_sum<<<8, 256, 0, stream>>>((const float*)d_in[10], (const float*)d_in[11], bs_c1, 2048);
  bias_sum<<<8, 256, 0, stream>>>((const float*)d_in[14], (const float*)d_in[15], bs_w0, 2048);
  bias_sum<<<8, 256, 0, stream>>>((const float*)d_in[18], (const float*)d_in[19], bs_w1, 2048);
  embed_gather<<<8192, 256, 0, stream>>>(cid, etab, ce_b, M * 128);

  const int G2048 = (M >> 7) * (2048 >> 7);   // 4096
  const int G512  = (M >> 7) * (512 >> 7);    // 1024
  if (fused) {
    gemm_lds<0, 1><<<G2048, 256, 0, stream>>>(ce_b, 128, wih_c0, bs_c0, xg_c, M, 2048, 128);
    gemm_lds<0, 1><<<G2048, 256, 0, stream>>>(we_b, 768, wih_w0, bs_w0, xg_w, M, 2048, 768);
    lstm_mfma<<<16, 1024, 0, stream>>>(whh_c0, xg_c, comb, 0,
                                       whh_w0, xg_w, comb, 512, T);
    gemm_lds<0, 1><<<G2048, 256, 0, stream>>>(comb, 1024, wih_c1, bs_c1, xg_c, M, 2048, 512);
    gemm_lds<0, 1><<<G2048, 256, 0, stream>>>(comb + 512, 1024, wih_w1, bs_w1, xg_w, M, 2048, 512);
    lstm_mfma<<<16, 1024, 0, stream>>>(whh_c1, xg_c, comb, 0,
                                       whh_w1, xg_w, comb, 512, T);
  } else {
    gemm_lds<0, 1><<<G2048, 256, 0, stream>>>(ce_b, 128, wih_c0, bs_c0, xg_c, M, 2048, 128);
    lstm_mfma<<<8, 1024, 0, stream>>>(whh_c0, xg_c, comb, 0, whh_c0, xg_c, comb, 0, T);
    gemm_lds<0, 1><<<G2048, 256, 0, stream>>>(comb, 1024, wih_c1, bs_c1, xg_c, M, 2048, 512);
    lstm_mfma<<<8, 1024, 0, stream>>>(whh_c1, xg_c, comb, 0, whh_c1, xg_c, comb, 0, T);
    gemm_lds<0, 1><<<G2048, 256, 0, stream>>>(we_b, 768, wih_w0, bs_w0, xg_c, M, 2048, 768);
    lstm_mfma<<<8, 1024, 0, stream>>>(whh_w0, xg_c, comb, 512, whh_w0, xg_c, comb, 512, T);
    gemm_lds<0, 1><<<G2048, 256, 0, stream>>>(comb + 512, 1024, wih_w1, bs_w1, xg_c, M, 2048, 512);
    lstm_mfma<<<8, 1024, 0, stream>>>(whh_w1, xg_c, comb, 512, whh_w1, xg_c, comb, 512, T);
  }
  // ---- classifier ----
  gemm_lds<1, 0><<<G512, 256, 0, stream>>>(comb, 1024, cls1b, (const float*)d_in[21], h1, M, 512, 1024);
  cls2_kernel<<<2048, 256, 0, stream>>>(h1, cls2b, (const float*)d_in[23], logits, M);
  // ---- CRF ----
  crf_num<<<64, 256, 0, stream>>>(logits, tags, (const float*)d_in[24], (const float*)d_in[25],
                                  (const float*)d_in[26], numb, T);
  crf_denom<<<64, 64, 0, stream>>>(logits, (const float*)d_in[24], (const float*)d_in[25],
                                   (const float*)d_in[26], denb, T);
  crf_final<<<1, 64, 0, stream>>>(numb, denb, (float*)d_out);
}